// Round 4
// baseline (410.565 us; speedup 1.0000x reference)
//
#include <hip/hip_runtime.h>
#include <hip/hip_fp16.h>
#include <hip/hip_cooperative_groups.h>

// SilkNNUE R15 — int8 gather in the R12 lane structure + 1-launch coop.
//   Model from R11-R14:
//     R12 (fp16): TA-bound  — 128 CL/row x 512 row/CU x ~2cyc = 54.6us ~= 52.5 meas.
//     R13 (int8): DS-bound  — 29 DS/row (24-shfl butterfly) ~= 43us floor, 55 meas.
//     R14: serial gather = exposed latency (VALUBusy 12%, 135us). Reverted.
//   R15 = 64 CL/row (int8) AND ~10 DS/row (R12 budget):
//     g=lane>>4 owns feature 4b+g, sub=lane&15 owns 8B of the 128B int8 row.
//     uint2 loads (4 x 128B segments/instr = 8 CL), 16-bit-slot masked adds
//     (R13-verified), 2-level xor butterfly (8 shfl, exact u32 adds),
//     g==0 dequant+ReLU -> same swizzled hT packet layout. Dense unchanged.
//   Launches: ONE cooperative kernel (absmax -> sync -> quantize -> sync ->
//   NNUE). R13 showed each extra small dispatch costs ~10-15us bench.

namespace cg = cooperative_groups;

typedef _Float16 h2v_t  __attribute__((ext_vector_type(2)));
typedef _Float16 half8  __attribute__((ext_vector_type(8)));
typedef float    f32x4  __attribute__((ext_vector_type(4)));

constexpr int RPB = 64;   // rows per chunk

__device__ inline unsigned cvt_pair(unsigned w, float sc, float cb) {
    float f0 = (float)(w & 0xffffu) * sc + cb;
    float f1 = (float)(w >> 16)     * sc + cb;
    h2v_t h;
    h[0] = (_Float16)fmaxf(f0, 0.f);
    h[1] = (_Float16)fmaxf(f1, 0.f);
    return __builtin_bit_cast(unsigned, h);
}

// ---------------- cooperative: absmax + quantize + fused NNUE --------------
__global__ __launch_bounds__(256, 8) void nnue_all(
    const int*    __restrict__ x,      // (N,32)
    const float4* __restrict__ emb4,   // (7424,128) fp32 as float4
    unsigned*     __restrict__ emb8,   // ws: (7425,128) u8 permuted (d0,d2,d1,d3)
    const float*  __restrict__ W2,
    const float*  __restrict__ W3,
    _Float16*     __restrict__ W2h,    // ws: (32,128) fp16
    _Float16*     __restrict__ W3h,    // ws: (32,64) fp16
    const float*  __restrict__ b2,
    const float*  __restrict__ b3,
    const float*  __restrict__ W4,     // (64,)
    float*        __restrict__ slots,  // ws: gridDim.x partial absmax
    float*        __restrict__ out, int n)
{
    // per-wave: hT = 16 rows x 16 uint4 (swizzled), later aliased by a2 tile
    __shared__ __align__(16) char hmem[4][4096];   // 16384 B
    // per-wave packed u16 indices (phases A/B reuse as red[])
    __shared__ __align__(16) char xmem[4][1024];   //  4096 B  (total 20480)

    const int tid  = threadIdx.x;
    const int lane = tid & 63;
    const int wave = tid >> 6;
    const int gstep = (int)gridDim.x * 256;

    // ===================== phase A: per-block absmax partial ===============
    {
        float* red = (float*)&xmem[0][0];
        const int n4 = 7424 * 32;
        float m = 0.f;
        for (int i = blockIdx.x * 256 + tid; i < n4; i += gstep) {
            float4 v = emb4[i];
            m = fmaxf(m, fmaxf(fmaxf(fabsf(v.x), fabsf(v.y)),
                               fmaxf(fabsf(v.z), fabsf(v.w))));
        }
        #pragma unroll
        for (int s = 1; s < 64; s <<= 1)
            m = fmaxf(m, __shfl_xor(m, s));
        if (lane == 0) red[wave] = m;
        __syncthreads();
        if (tid == 0)
            slots[blockIdx.x] = fmaxf(fmaxf(red[0], red[1]),
                                      fmaxf(red[2], red[3]));
        __syncthreads();
    }
    __threadfence();
    cg::this_grid().sync();

    // ===================== phase B: reduce + quantize ======================
    float amax;
    {
        float* red = (float*)&xmem[0][0];
        float m = 0.f;
        const int nb = (int)gridDim.x;
        for (int i = tid; i < nb; i += 256) m = fmaxf(m, slots[i]);
        #pragma unroll
        for (int s = 1; s < 64; s <<= 1)
            m = fmaxf(m, __shfl_xor(m, s));
        if (lane == 0) red[wave] = m;
        __syncthreads();
        amax = fmaxf(fmaxf(red[0], red[1]), fmaxf(red[2], red[3]));
        amax = fmaxf(amax, 1e-20f);
        __syncthreads();    // red (xmem) dead before staging reuses it
    }
    const float qs = 127.f / amax;
    {
        for (int i = blockIdx.x * 256 + tid; i < 7425 * 32; i += gstep) {
            unsigned w = 0x80808080u;              // zero row 7424: q=0
            if (i < 7424 * 32) {
                float4 v = emb4[i];
                int q0 = min(127, max(-127, (int)rintf(v.x * qs)));
                int q1 = min(127, max(-127, (int)rintf(v.y * qs)));
                int q2 = min(127, max(-127, (int)rintf(v.z * qs)));
                int q3 = min(127, max(-127, (int)rintf(v.w * qs)));
                // byte order (d0,d2,d1,d3): lo-mask slots = dims (4j,4j+1),
                // hi-perm slots = dims (4j+2,4j+3)
                w = (unsigned)(q0 + 128)
                  | ((unsigned)(q2 + 128) << 8)
                  | ((unsigned)(q1 + 128) << 16)
                  | ((unsigned)(q3 + 128) << 24);
            }
            emb8[i] = w;
        }
        for (int i = blockIdx.x * 256 + tid; i < 4096; i += gstep)
            W2h[i] = (_Float16)W2[i];
        for (int i = blockIdx.x * 256 + tid; i < 2048; i += gstep)
            W3h[i] = (_Float16)W3[i];
    }
    __threadfence();
    cg::this_grid().sync();

    // ===================== phase C: fused NNUE =============================
    const float sc = amax * (1.f / 127.f);
    const float cb = -4096.f * sc;      // bias removal: 32 features x 128
    const int g   = lane >> 4;          // feature subgroup 0..3
    const int sub = lane & 15;          // 8B sub-packet of 128B int8 row
    const unsigned subOff = (unsigned)sub * 8u;
    const char* embb = (const char*)emb8;

    unsigned short* xw = (unsigned short*)&xmem[wave][0];
    const int nchunks = (n + RPB - 1) / RPB;

    for (int chunk = blockIdx.x; chunk < nchunks; chunk += gridDim.x) {
        const int row0  = chunk * RPB;
        const int wrow0 = __builtin_amdgcn_readfirstlane(row0 + wave * 16);

        // ---- stage indices packed u16 (features 29..31 -> zero row 7424) --
        {
            const int4* xb = (const int4*)(x + (size_t)wrow0 * 32);
            int4 a = xb[lane * 2];
            int4 b = xb[lane * 2 + 1];
            if ((lane & 3) == 3) { b.y = 7424; b.z = 7424; b.w = 7424; }
            uint4 pk;
            pk.x = ((unsigned)a.x & 0xffffu) | ((unsigned)a.y << 16);
            pk.y = ((unsigned)a.z & 0xffffu) | ((unsigned)a.w << 16);
            pk.z = ((unsigned)b.x & 0xffffu) | ((unsigned)b.y << 16);
            pk.w = ((unsigned)b.z & 0xffffu) | ((unsigned)b.w << 16);
            ((uint4*)xw)[lane] = pk;
        }
        // same-wave DS ordering; no barriers in this phase.

        // ---- gather: 8 x uint2 per row (64 CL/row), 16-bit-slot adds ------
        #pragma unroll 4
        for (int r = 0; r < 16; ++r) {
            const unsigned short* xrow = xw + r * 32 + g;
            uint2 v[8];
            #pragma unroll
            for (int b = 0; b < 8; ++b) {
                const unsigned idx = xrow[4 * b];        // ds_read_u16 bcast
                v[b] = *(const uint2*)(embb + ((idx << 7) + subOff));
            }
            unsigned aL0 = 0, aH0 = 0, aL1 = 0, aH1 = 0;
            #pragma unroll
            for (int b = 0; b < 8; ++b) {
                aL0 += v[b].x & 0x00ff00ffu;
                aH0 += __builtin_amdgcn_perm(0u, v[b].x, 0x0c030c01u);
                aL1 += v[b].y & 0x00ff00ffu;
                aH1 += __builtin_amdgcn_perm(0u, v[b].y, 0x0c030c01u);
            }
            // 2-level butterfly over g (lane bits 4,5): exact u32 adds,
            // slot max 32*255 = 8160 < 65536.
            aL0 += (unsigned)__shfl_xor((int)aL0, 16);
            aL0 += (unsigned)__shfl_xor((int)aL0, 32);
            aH0 += (unsigned)__shfl_xor((int)aH0, 16);
            aH0 += (unsigned)__shfl_xor((int)aH0, 32);
            aL1 += (unsigned)__shfl_xor((int)aL1, 16);
            aL1 += (unsigned)__shfl_xor((int)aL1, 32);
            aH1 += (unsigned)__shfl_xor((int)aH1, 16);
            aH1 += (unsigned)__shfl_xor((int)aH1, 32);
            if (g == 0) {   // lane sub holds dims 8sub..8sub+7 = packet sub
                uint4 o;
                o.x = cvt_pair(aL0, sc, cb);
                o.y = cvt_pair(aH0, sc, cb);
                o.z = cvt_pair(aL1, sc, cb);
                o.w = cvt_pair(aH1, sc, cb);
                ((uint4*)&hmem[wave][0])[r * 16 + (sub ^ (r & 7))] = o;
            }
        }

        // ============ dense (per-wave MFMA, same wave's 16 rows) ===========
        const uint4* hT = (const uint4*)&hmem[wave][0];
        const int q  = lane >> 4;     // k-quad
        const int nn = lane & 15;     // A row m / B col n / C col n

        half8 bw2[2][4];
        #pragma unroll
        for (int nt = 0; nt < 2; ++nt)
            #pragma unroll
            for (int kk = 0; kk < 4; ++kk)
                bw2[nt][kk] = __builtin_bit_cast(half8,
                    *(const uint4*)((const char*)W2h +
                        ((nt * 16 + nn) * 128 + kk * 32 + q * 8) * 2));

        half8 af[4];
        #pragma unroll
        for (int kk = 0; kk < 4; ++kk)
            af[kk] = __builtin_bit_cast(half8,
                hT[nn * 16 + ((4 * kk + q) ^ (nn & 7))]);

        f32x4 acc0 = {0.f, 0.f, 0.f, 0.f}, acc1 = {0.f, 0.f, 0.f, 0.f};
        #pragma unroll
        for (int kk = 0; kk < 4; ++kk) {
            acc0 = __builtin_amdgcn_mfma_f32_16x16x32_f16(af[kk], bw2[0][kk], acc0, 0, 0, 0);
            acc1 = __builtin_amdgcn_mfma_f32_16x16x32_f16(af[kk], bw2[1][kk], acc1, 0, 0, 0);
        }
        const float bb0 = b2[nn], bb1 = b2[16 + nn];

        // CReLU + transpose via LDS (stride 68 halfs). a2 aliases hT:
        // all hT (af) reads completed above, same-wave program order.
        _Float16* a2 = (_Float16*)&hmem[wave][0];
        #pragma unroll
        for (int r = 0; r < 4; ++r) {
            const float v0 = acc0[r] + bb0;
            const float v1 = acc1[r] + bb1;
            const int m = q * 4 + r;
            a2[m * 68 + nn]      = (_Float16)fmaxf(v0, 0.f);
            a2[m * 68 + 16 + nn] = (_Float16)fmaxf(v1, 0.f);
            a2[m * 68 + 32 + nn] = (_Float16)fmaxf(-v0, 0.f);
            a2[m * 68 + 48 + nn] = (_Float16)fmaxf(-v1, 0.f);
        }

        half8 bw3[2][2];
        #pragma unroll
        for (int nt = 0; nt < 2; ++nt)
            #pragma unroll
            for (int kk = 0; kk < 2; ++kk)
                bw3[nt][kk] = __builtin_bit_cast(half8,
                    *(const uint4*)((const char*)W3h +
                        ((nt * 16 + nn) * 64 + kk * 32 + q * 8) * 2));

        half8 a2f[2];
        #pragma unroll
        for (int kk = 0; kk < 2; ++kk) {
            const _Float16* pp = &a2[nn * 68 + kk * 32 + q * 8];
            half8 t;
            #pragma unroll
            for (int j = 0; j < 8; ++j) t[j] = pp[j];
            a2f[kk] = t;
        }

        f32x4 acc30 = {0.f, 0.f, 0.f, 0.f}, acc31 = {0.f, 0.f, 0.f, 0.f};
        #pragma unroll
        for (int kk = 0; kk < 2; ++kk) {
            acc30 = __builtin_amdgcn_mfma_f32_16x16x32_f16(a2f[kk], bw3[0][kk], acc30, 0, 0, 0);
            acc31 = __builtin_amdgcn_mfma_f32_16x16x32_f16(a2f[kk], bw3[1][kk], acc31, 0, 0, 0);
        }
        const float bb30 = b3[nn], bb31 = b3[16 + nn];

        const float w4a = W4[nn],      w4b = W4[16 + nn];
        const float w4c = W4[32 + nn], w4d = W4[48 + nn];
        float o[4];
        #pragma unroll
        for (int r = 0; r < 4; ++r) {
            const float v0 = acc30[r] + bb30;
            const float v1 = acc31[r] + bb31;
            o[r] = fmaxf(v0, 0.f) * w4a + fmaxf(-v0, 0.f) * w4c
                 + fmaxf(v1, 0.f) * w4b + fmaxf(-v1, 0.f) * w4d;
        }
        #pragma unroll
        for (int s = 1; s < 16; s <<= 1) {
            #pragma unroll
            for (int r = 0; r < 4; ++r) o[r] += __shfl_xor(o[r], s);
        }
        if (nn == 0) {
            #pragma unroll
            for (int r = 0; r < 4; ++r) {
                const int row = wrow0 + q * 4 + r;
                if (row < n) out[row] = o[r];
            }
        }
    }
}

// ---------------- fallback (fp16 table + fp32-weight fused) ----------------
__global__ __launch_bounds__(256) void prep_fp16(
    const float* __restrict__ emb, __half2* __restrict__ emb16,
    int npairs_real, int npairs_tot)
{
    int i = blockIdx.x * blockDim.x + threadIdx.x;
    if (i < npairs_tot) {
        float2 v = make_float2(0.f, 0.f);
        if (i < npairs_real) v = ((const float2*)emb)[i];
        emb16[i] = __floats2half2_rn(v.x, v.y);
    }
}

__global__ __launch_bounds__(256) void nnue_fused(
    const int*    __restrict__ x,
    const __half* __restrict__ emb16,
    const float*  __restrict__ W2, const float* __restrict__ b2,
    const float*  __restrict__ W3, const float* __restrict__ b3,
    const float*  __restrict__ W4,
    float*        __restrict__ out, int n)
{
    __shared__ int     xlds[4][512];
    __shared__ __half2 hbuf[64][65];
    __shared__ float   h2T[32 * 64];
    __shared__ float   obuf[4][64];

    const int tid  = threadIdx.x;
    const int lane = tid & 63;
    const int wave = tid >> 6;
    const int row0 = blockIdx.x * RPB;
    const int wrow0 = __builtin_amdgcn_readfirstlane(row0 + wave * 16);
    const int g   = lane >> 4;
    const int sub = lane & 15;
    const unsigned subOff = (unsigned)sub * 16u;

    {
        const int4* xb = (const int4*)(x + (size_t)wrow0 * 32);
        int4 a = xb[lane * 2];
        int4 b = xb[lane * 2 + 1];
        if ((lane & 3) == 3) { b.y = 7424; b.z = 7424; b.w = 7424; }
        ((int4*)&xlds[wave][0])[lane * 2]     = a;
        ((int4*)&xlds[wave][0])[lane * 2 + 1] = b;
    }

    #pragma unroll 4
    for (int r = 0; r < 16; ++r) {
        const int* xrow = &xlds[wave][r * 32 + g];
        uint4 v[8];
        #pragma unroll
        for (int b = 0; b < 8; ++b) {
            const int idx = xrow[4 * b];
            const unsigned off = ((unsigned)idx << 8) + subOff;
            v[b] = *(const uint4*)((const char*)emb16 + off);
        }
        h2v_t hacc[4];
        #pragma unroll
        for (int q = 0; q < 4; ++q) hacc[q] = (h2v_t)0;
        #pragma unroll
        for (int b = 0; b < 8; ++b) {
            hacc[0] += __builtin_bit_cast(h2v_t, v[b].x);
            hacc[1] += __builtin_bit_cast(h2v_t, v[b].y);
            hacc[2] += __builtin_bit_cast(h2v_t, v[b].z);
            hacc[3] += __builtin_bit_cast(h2v_t, v[b].w);
        }
        #pragma unroll
        for (int q = 0; q < 4; ++q) {
            unsigned u = __builtin_bit_cast(unsigned, hacc[q]);
            h2v_t t = __builtin_bit_cast(h2v_t, u);
            t += __builtin_bit_cast(h2v_t, (unsigned)__shfl_xor((int)u, 16));
            unsigned u2 = __builtin_bit_cast(unsigned, t);
            t += __builtin_bit_cast(h2v_t, (unsigned)__shfl_xor((int)u2, 32));
            hacc[q] = __builtin_elementwise_max(t, (h2v_t)0);
        }
        if (g == 0) {
            const int row = wave * 16 + r;
            #pragma unroll
            for (int q = 0; q < 4; ++q)
                hbuf[row][sub * 4 + q] = __builtin_bit_cast(__half2, hacc[q]);
        }
    }
    __syncthreads();

    {
        const int j0 = wave * 8;
        const int rr = lane;
        float acc[8];
        #pragma unroll
        for (int j = 0; j < 8; ++j) acc[j] = b2[j0 + j];
        #pragma unroll
        for (int d2 = 0; d2 < 64; ++d2) {
            const __half2 hv = hbuf[rr][d2];
            const float vx = __low2float(hv), vy = __high2float(hv);
            #pragma unroll
            for (int j = 0; j < 8; ++j) {
                const float* w = W2 + (size_t)(j0 + j) * 128 + d2 * 2;
                acc[j] = fmaf(vx, w[0], acc[j]);
                acc[j] = fmaf(vy, w[1], acc[j]);
            }
        }
        #pragma unroll
        for (int j = 0; j < 8; ++j) h2T[(j0 + j) * 64 + rr] = acc[j];
    }
    __syncthreads();

    {
        const int j0 = wave * 8;
        const int rr = lane;
        float h2v[32];
        #pragma unroll
        for (int k = 0; k < 32; ++k) h2v[k] = h2T[k * 64 + rr];
        float acc[8];
        #pragma unroll
        for (int j = 0; j < 8; ++j) acc[j] = b3[j0 + j];
        #pragma unroll
        for (int k = 0; k < 32; ++k) {
            const float pz = fmaxf(h2v[k], 0.f);
            const float mz = fmaxf(-h2v[k], 0.f);
            #pragma unroll
            for (int j = 0; j < 8; ++j) {
                const float* w = W3 + (size_t)(j0 + j) * 64;
                acc[j] = fmaf(pz, w[k],      acc[j]);
                acc[j] = fmaf(mz, w[32 + k], acc[j]);
            }
        }
        float o = 0.f;
        #pragma unroll
        for (int j = 0; j < 8; ++j) {
            const int jj = j0 + j;
            o = fmaf(fmaxf(acc[j], 0.f),  W4[jj],      o);
            o = fmaf(fmaxf(-acc[j], 0.f), W4[32 + jj], o);
        }
        obuf[wave][rr] = o;
    }
    __syncthreads();

    if (tid < 64) {
        const int row = row0 + tid;
        if (row < n)
            out[row] = obuf[0][tid] + obuf[1][tid] + obuf[2][tid] + obuf[3][tid];
    }
}

extern "C" void kernel_launch(void* const* d_in, const int* in_sizes, int n_in,
                              void* d_out, int out_size, void* d_ws, size_t ws_size,
                              hipStream_t stream) {
    const int*   x   = (const int*)  d_in[0];
    const float* emb = (const float*)d_in[1];
    const float* W2  = (const float*)d_in[2];
    const float* b2  = (const float*)d_in[3];
    const float* W3  = (const float*)d_in[4];
    const float* b3  = (const float*)d_in[5];
    const float* W4  = (const float*)d_in[6];
    float* out = (float*)d_out;
    const int n = out_size;                 // 131072 rows

    // workspace layout (16B-aligned sections)
    const size_t emb8_bytes = (size_t)7425 * 128;           // 950,400
    const size_t w2h_off    = emb8_bytes;                   // +8192
    const size_t w3h_off    = w2h_off + 8192;               // +4096
    const size_t slots_off  = w3h_off + 4096;               // +8192 (2048 f32)
    const size_t need       = slots_off + 8192;

    if (ws_size >= need) {
        unsigned*     emb8  = (unsigned*)d_ws;
        _Float16*     W2h   = (_Float16*)((char*)d_ws + w2h_off);
        _Float16*     W3h   = (_Float16*)((char*)d_ws + w3h_off);
        float*        slots = (float*)((char*)d_ws + slots_off);
        const float4* emb4  = (const float4*)emb;

        static int nb_cached = 0;
        if (nb_cached == 0) {
            int bpc = 0;
            if (hipOccupancyMaxActiveBlocksPerMultiprocessor(
                    &bpc, nnue_all, 256, 0) != hipSuccess || bpc < 1)
                bpc = 4;
            int nb = bpc * 256;                 // 256 CUs on MI355X
            if (nb > 2048) nb = 2048;           // = nchunks
            nb_cached = nb;
        }

        int n_arg = n;
        void* args[] = {(void*)&x, (void*)&emb4, (void*)&emb8,
                        (void*)&W2, (void*)&W3, (void*)&W2h, (void*)&W3h,
                        (void*)&b2, (void*)&b3, (void*)&W4,
                        (void*)&slots, (void*)&out, (void*)&n_arg};
        hipLaunchCooperativeKernel((void*)nnue_all, dim3(nb_cached), dim3(256),
                                   args, 0, stream);
    } else {
        // legacy fallback: fp16 table + fp32-weight fused kernel
        __half2* emb16 = (__half2*)d_ws;
        const int npairs_real = 7424 * 64;
        const int npairs_tot  = 7425 * 64;
        hipLaunchKernelGGL(prep_fp16, dim3((npairs_tot + 255) / 256), dim3(256),
                           0, stream, emb, emb16, npairs_real, npairs_tot);
        hipLaunchKernelGGL(nnue_fused, dim3((n + RPB - 1) / RPB), dim3(256),
                           0, stream, x, (const __half*)emb16, W2, b2, W3, b3,
                           W4, out, n);
    }
}

// Round 5
// 120.683 us; speedup vs baseline: 3.4020x; 3.4020x over previous
//
#include <hip/hip_runtime.h>
#include <hip/hip_fp16.h>

// SilkNNUE R16 — R15's verified int8 gather (phase C) as a PLAIN kernel.
//   R15 post-mortem: cooperative grid.sync with 2048 blocks costs ~480us
//   (device-scope atomic spin -> 85MB of HBM RMW traffic). NEVER use coop
//   grid sync here. Phase C itself is numerically verified (R15 passed,
//   absmax 4.88e-4) but was never timed clean.
//   Model: R12 (fp16) sits at the L2 random-request wall (16.8M CL / 8 XCD
//   / 52.5us ~= 16.8 CL/cyc/XCD ~= 1/channel/cyc). R13 halved CL but was
//   DS-bound (29 DS-ops/row). R16 = 64 CL/row AND ~10 DS-ops/row:
//     g=lane>>4 owns feature 4b+g, sub=lane&15 owns 8B of the 128B int8
//     row. uint2 loads, 16-bit-slot masked adds (exact), 2-level butterfly
//     (8 shfl), g==0 dequant+ReLU -> swizzled hT. Dense MFMA unchanged.
//   Chain: absmax_partial (512 slots, no init/atomics) -> prep_q8 (slot
//   reduce + quantize + W2h/W3h + amax publish) -> nnue_q8. 3 dispatches,
//   no memset, no atomics, no coop.

typedef _Float16 h2v_t  __attribute__((ext_vector_type(2)));
typedef _Float16 half8  __attribute__((ext_vector_type(8)));
typedef float    f32x4  __attribute__((ext_vector_type(4)));

constexpr int RPB    = 64;    // rows per block (main kernel)
constexpr int NSLOTS = 512;   // absmax partial slots

// ---- pass 1: per-block absmax partials (no init, no atomics) --------------
__global__ __launch_bounds__(256) void absmax_partial(
    const float4* __restrict__ emb4, float* __restrict__ slots, int n4)
{
    __shared__ float red[4];
    float m = 0.f;
    const int stride = NSLOTS * 256;
    for (int i = blockIdx.x * 256 + threadIdx.x; i < n4; i += stride) {
        float4 v = emb4[i];
        m = fmaxf(m, fmaxf(fmaxf(fabsf(v.x), fabsf(v.y)),
                           fmaxf(fabsf(v.z), fabsf(v.w))));
    }
    #pragma unroll
    for (int s = 1; s < 64; s <<= 1)
        m = fmaxf(m, __shfl_xor(m, s));
    if ((threadIdx.x & 63) == 0) red[threadIdx.x >> 6] = m;
    __syncthreads();
    if (threadIdx.x == 0)
        slots[blockIdx.x] = fmaxf(fmaxf(red[0], red[1]), fmaxf(red[2], red[3]));
}

// ---- pass 2: reduce slots + quantize emb -> u8 + W2/W3 -> fp16 ------------
__global__ __launch_bounds__(256) void prep_q8(
    const float4* __restrict__ emb4, unsigned* __restrict__ emb8,
    const float* __restrict__ W2, const float* __restrict__ W3,
    _Float16* __restrict__ W2h, _Float16* __restrict__ W3h,
    const float* __restrict__ slots, float* __restrict__ amax_out)
{
    __shared__ float red[4];
    const int tid = threadIdx.x;
    // block-local reduce of the 512 partials (2KB, L2-hot)
    float m = fmaxf(slots[tid], slots[tid + 256]);
    #pragma unroll
    for (int s = 1; s < 64; s <<= 1)
        m = fmaxf(m, __shfl_xor(m, s));
    if ((tid & 63) == 0) red[tid >> 6] = m;
    __syncthreads();
    const float amax = fmaxf(fmaxf(fmaxf(red[0], red[1]),
                                   fmaxf(red[2], red[3])), 1e-20f);
    const float qs = 127.f / amax;

    const int i = blockIdx.x * 256 + tid;
    if (i == 0) *amax_out = amax;
    if (i < 7425 * 32) {
        unsigned w = 0x80808080u;              // zero row 7424: q=0
        if (i < 7424 * 32) {
            float4 v = emb4[i];
            int q0 = min(127, max(-127, (int)rintf(v.x * qs)));
            int q1 = min(127, max(-127, (int)rintf(v.y * qs)));
            int q2 = min(127, max(-127, (int)rintf(v.z * qs)));
            int q3 = min(127, max(-127, (int)rintf(v.w * qs)));
            // byte order (d0,d2,d1,d3): lo-mask slots = dims (4j,4j+1),
            // hi-perm slots = dims (4j+2,4j+3)
            w = (unsigned)(q0 + 128)
              | ((unsigned)(q2 + 128) << 8)
              | ((unsigned)(q1 + 128) << 16)
              | ((unsigned)(q3 + 128) << 24);
        }
        emb8[i] = w;
    }
    if (i < 4096) W2h[i] = (_Float16)W2[i];
    if (i < 2048) W3h[i] = (_Float16)W3[i];
}

__device__ inline unsigned cvt_pair(unsigned w, float sc, float cb) {
    float f0 = (float)(w & 0xffffu) * sc + cb;
    float f1 = (float)(w >> 16)     * sc + cb;
    h2v_t h;
    h[0] = (_Float16)fmaxf(f0, 0.f);
    h[1] = (_Float16)fmaxf(f1, 0.f);
    return __builtin_bit_cast(unsigned, h);
}

// ---------------- fused kernel (int8 gather, R15 phase C) ------------------
__global__ __launch_bounds__(256, 8) void nnue_q8(
    const int*      __restrict__ x,      // (N,32)
    const unsigned* __restrict__ emb8,   // (7425,128) u8 permuted
    const _Float16* __restrict__ W2h,    // (32,128) fp16
    const _Float16* __restrict__ W3h,    // (32,64) fp16
    const float*    __restrict__ b2,
    const float*    __restrict__ b3,
    const float*    __restrict__ W4,     // (64,)
    const float*    __restrict__ amaxp,
    float*          __restrict__ out, int n)
{
    // per-wave: hT = 16 rows x 16 uint4 (swizzled), later aliased by a2 tile
    __shared__ __align__(16) char hmem[4][4096];   // 16384 B
    // per-wave packed u16 indices
    __shared__ __align__(16) char xmem[4][1024];   //  4096 B  (total 20480)

    const int tid  = threadIdx.x;
    const int lane = tid & 63;
    const int wave = tid >> 6;
    const int row0 = blockIdx.x * RPB;
    const int wrow0 = __builtin_amdgcn_readfirstlane(row0 + wave * 16);

    const float amax = *amaxp;
    const float sc = amax * (1.f / 127.f);
    const float cb = -4096.f * sc;      // bias removal: 32 features x 128

    const int g   = lane >> 4;          // feature subgroup 0..3
    const int sub = lane & 15;          // 8B sub-packet of 128B int8 row
    const unsigned subOff = (unsigned)sub * 8u;
    const char* embb = (const char*)emb8;

    unsigned short* xw = (unsigned short*)&xmem[wave][0];

    // ---- stage indices packed u16 (features 29..31 -> zero row 7424) ------
    {
        const int4* xb = (const int4*)(x + (size_t)wrow0 * 32);
        int4 a = xb[lane * 2];
        int4 b = xb[lane * 2 + 1];
        if ((lane & 3) == 3) { b.y = 7424; b.z = 7424; b.w = 7424; }
        uint4 pk;
        pk.x = ((unsigned)a.x & 0xffffu) | ((unsigned)a.y << 16);
        pk.y = ((unsigned)a.z & 0xffffu) | ((unsigned)a.w << 16);
        pk.z = ((unsigned)b.x & 0xffffu) | ((unsigned)b.y << 16);
        pk.w = ((unsigned)b.z & 0xffffu) | ((unsigned)b.w << 16);
        ((uint4*)xw)[lane] = pk;
    }
    // same-wave DS ordering; no barriers anywhere in this kernel.

    // ---- gather: 8 x uint2 per row (64 CL/row), 16-bit-slot adds ----------
    #pragma unroll 4
    for (int r = 0; r < 16; ++r) {
        const unsigned short* xrow = xw + r * 32 + g;
        uint2 v[8];
        #pragma unroll
        for (int b = 0; b < 8; ++b) {
            const unsigned idx = xrow[4 * b];        // ds_read_u16 bcast
            v[b] = *(const uint2*)(embb + ((idx << 7) + subOff));
        }
        unsigned aL0 = 0, aH0 = 0, aL1 = 0, aH1 = 0;
        #pragma unroll
        for (int b = 0; b < 8; ++b) {
            aL0 += v[b].x & 0x00ff00ffu;
            aH0 += __builtin_amdgcn_perm(0u, v[b].x, 0x0c030c01u);
            aL1 += v[b].y & 0x00ff00ffu;
            aH1 += __builtin_amdgcn_perm(0u, v[b].y, 0x0c030c01u);
        }
        // 2-level butterfly over g (lane bits 4,5): exact u32 adds,
        // slot max 32*255 = 8160 < 65536.
        aL0 += (unsigned)__shfl_xor((int)aL0, 16);
        aL0 += (unsigned)__shfl_xor((int)aL0, 32);
        aH0 += (unsigned)__shfl_xor((int)aH0, 16);
        aH0 += (unsigned)__shfl_xor((int)aH0, 32);
        aL1 += (unsigned)__shfl_xor((int)aL1, 16);
        aL1 += (unsigned)__shfl_xor((int)aL1, 32);
        aH1 += (unsigned)__shfl_xor((int)aH1, 16);
        aH1 += (unsigned)__shfl_xor((int)aH1, 32);
        if (g == 0) {   // lane sub holds dims 8sub..8sub+7 = packet sub
            uint4 o;
            o.x = cvt_pair(aL0, sc, cb);
            o.y = cvt_pair(aH0, sc, cb);
            o.z = cvt_pair(aL1, sc, cb);
            o.w = cvt_pair(aH1, sc, cb);
            ((uint4*)&hmem[wave][0])[r * 16 + (sub ^ (r & 7))] = o;
        }
    }

    // ================= dense (per-wave MFMA, same wave's 16 rows) ==========
    const uint4* hT = (const uint4*)&hmem[wave][0];
    const int q  = lane >> 4;     // k-quad
    const int nn = lane & 15;     // A row m / B col n / C col n

    half8 bw2[2][4];
    #pragma unroll
    for (int nt = 0; nt < 2; ++nt)
        #pragma unroll
        for (int kk = 0; kk < 4; ++kk)
            bw2[nt][kk] = __builtin_bit_cast(half8,
                *(const uint4*)((const char*)W2h +
                    ((nt * 16 + nn) * 128 + kk * 32 + q * 8) * 2));

    half8 af[4];
    #pragma unroll
    for (int kk = 0; kk < 4; ++kk)
        af[kk] = __builtin_bit_cast(half8,
            hT[nn * 16 + ((4 * kk + q) ^ (nn & 7))]);

    f32x4 acc0 = {0.f, 0.f, 0.f, 0.f}, acc1 = {0.f, 0.f, 0.f, 0.f};
    #pragma unroll
    for (int kk = 0; kk < 4; ++kk) {
        acc0 = __builtin_amdgcn_mfma_f32_16x16x32_f16(af[kk], bw2[0][kk], acc0, 0, 0, 0);
        acc1 = __builtin_amdgcn_mfma_f32_16x16x32_f16(af[kk], bw2[1][kk], acc1, 0, 0, 0);
    }
    const float bb0 = b2[nn], bb1 = b2[16 + nn];

    // CReLU + transpose via LDS (stride 68 halfs). a2 aliases hT:
    // all hT (af) reads completed above, same-wave program order.
    _Float16* a2 = (_Float16*)&hmem[wave][0];
    #pragma unroll
    for (int r = 0; r < 4; ++r) {
        const float v0 = acc0[r] + bb0;
        const float v1 = acc1[r] + bb1;
        const int m = q * 4 + r;
        a2[m * 68 + nn]      = (_Float16)fmaxf(v0, 0.f);
        a2[m * 68 + 16 + nn] = (_Float16)fmaxf(v1, 0.f);
        a2[m * 68 + 32 + nn] = (_Float16)fmaxf(-v0, 0.f);
        a2[m * 68 + 48 + nn] = (_Float16)fmaxf(-v1, 0.f);
    }

    half8 bw3[2][2];
    #pragma unroll
    for (int nt = 0; nt < 2; ++nt)
        #pragma unroll
        for (int kk = 0; kk < 2; ++kk)
            bw3[nt][kk] = __builtin_bit_cast(half8,
                *(const uint4*)((const char*)W3h +
                    ((nt * 16 + nn) * 64 + kk * 32 + q * 8) * 2));

    half8 a2f[2];
    #pragma unroll
    for (int kk = 0; kk < 2; ++kk) {
        const _Float16* pp = &a2[nn * 68 + kk * 32 + q * 8];
        half8 t;
        #pragma unroll
        for (int j = 0; j < 8; ++j) t[j] = pp[j];
        a2f[kk] = t;
    }

    f32x4 acc30 = {0.f, 0.f, 0.f, 0.f}, acc31 = {0.f, 0.f, 0.f, 0.f};
    #pragma unroll
    for (int kk = 0; kk < 2; ++kk) {
        acc30 = __builtin_amdgcn_mfma_f32_16x16x32_f16(a2f[kk], bw3[0][kk], acc30, 0, 0, 0);
        acc31 = __builtin_amdgcn_mfma_f32_16x16x32_f16(a2f[kk], bw3[1][kk], acc31, 0, 0, 0);
    }
    const float bb30 = b3[nn], bb31 = b3[16 + nn];

    const float w4a = W4[nn],      w4b = W4[16 + nn];
    const float w4c = W4[32 + nn], w4d = W4[48 + nn];
    float o[4];
    #pragma unroll
    for (int r = 0; r < 4; ++r) {
        const float v0 = acc30[r] + bb30;
        const float v1 = acc31[r] + bb31;
        o[r] = fmaxf(v0, 0.f) * w4a + fmaxf(-v0, 0.f) * w4c
             + fmaxf(v1, 0.f) * w4b + fmaxf(-v1, 0.f) * w4d;
    }
    #pragma unroll
    for (int s = 1; s < 16; s <<= 1) {
        #pragma unroll
        for (int r = 0; r < 4; ++r) o[r] += __shfl_xor(o[r], s);
    }
    if (nn == 0) {
        #pragma unroll
        for (int r = 0; r < 4; ++r) {
            const int row = wrow0 + q * 4 + r;
            if (row < n) out[row] = o[r];
        }
    }
}

// ---------------- fallback (fp16 table + fp32-weight fused) ----------------
__global__ __launch_bounds__(256) void prep_fp16(
    const float* __restrict__ emb, __half2* __restrict__ emb16,
    int npairs_real, int npairs_tot)
{
    int i = blockIdx.x * blockDim.x + threadIdx.x;
    if (i < npairs_tot) {
        float2 v = make_float2(0.f, 0.f);
        if (i < npairs_real) v = ((const float2*)emb)[i];
        emb16[i] = __floats2half2_rn(v.x, v.y);
    }
}

__global__ __launch_bounds__(256) void nnue_fused(
    const int*    __restrict__ x,
    const __half* __restrict__ emb16,
    const float*  __restrict__ W2, const float* __restrict__ b2,
    const float*  __restrict__ W3, const float* __restrict__ b3,
    const float*  __restrict__ W4,
    float*        __restrict__ out, int n)
{
    __shared__ int     xlds[4][512];
    __shared__ __half2 hbuf[64][65];
    __shared__ float   h2T[32 * 64];
    __shared__ float   obuf[4][64];

    const int tid  = threadIdx.x;
    const int lane = tid & 63;
    const int wave = tid >> 6;
    const int row0 = blockIdx.x * RPB;
    const int wrow0 = __builtin_amdgcn_readfirstlane(row0 + wave * 16);
    const int g   = lane >> 4;
    const int sub = lane & 15;
    const unsigned subOff = (unsigned)sub * 16u;

    {
        const int4* xb = (const int4*)(x + (size_t)wrow0 * 32);
        int4 a = xb[lane * 2];
        int4 b = xb[lane * 2 + 1];
        if ((lane & 3) == 3) { b.y = 7424; b.z = 7424; b.w = 7424; }
        ((int4*)&xlds[wave][0])[lane * 2]     = a;
        ((int4*)&xlds[wave][0])[lane * 2 + 1] = b;
    }

    #pragma unroll 4
    for (int r = 0; r < 16; ++r) {
        const int* xrow = &xlds[wave][r * 32 + g];
        uint4 v[8];
        #pragma unroll
        for (int b = 0; b < 8; ++b) {
            const int idx = xrow[4 * b];
            const unsigned off = ((unsigned)idx << 8) + subOff;
            v[b] = *(const uint4*)((const char*)emb16 + off);
        }
        h2v_t hacc[4];
        #pragma unroll
        for (int q = 0; q < 4; ++q) hacc[q] = (h2v_t)0;
        #pragma unroll
        for (int b = 0; b < 8; ++b) {
            hacc[0] += __builtin_bit_cast(h2v_t, v[b].x);
            hacc[1] += __builtin_bit_cast(h2v_t, v[b].y);
            hacc[2] += __builtin_bit_cast(h2v_t, v[b].z);
            hacc[3] += __builtin_bit_cast(h2v_t, v[b].w);
        }
        #pragma unroll
        for (int q = 0; q < 4; ++q) {
            unsigned u = __builtin_bit_cast(unsigned, hacc[q]);
            h2v_t t = __builtin_bit_cast(h2v_t, u);
            t += __builtin_bit_cast(h2v_t, (unsigned)__shfl_xor((int)u, 16));
            unsigned u2 = __builtin_bit_cast(unsigned, t);
            t += __builtin_bit_cast(h2v_t, (unsigned)__shfl_xor((int)u2, 32));
            hacc[q] = __builtin_elementwise_max(t, (h2v_t)0);
        }
        if (g == 0) {
            const int row = wave * 16 + r;
            #pragma unroll
            for (int q = 0; q < 4; ++q)
                hbuf[row][sub * 4 + q] = __builtin_bit_cast(__half2, hacc[q]);
        }
    }
    __syncthreads();

    {
        const int j0 = wave * 8;
        const int rr = lane;
        float acc[8];
        #pragma unroll
        for (int j = 0; j < 8; ++j) acc[j] = b2[j0 + j];
        #pragma unroll
        for (int d2 = 0; d2 < 64; ++d2) {
            const __half2 hv = hbuf[rr][d2];
            const float vx = __low2float(hv), vy = __high2float(hv);
            #pragma unroll
            for (int j = 0; j < 8; ++j) {
                const float* w = W2 + (size_t)(j0 + j) * 128 + d2 * 2;
                acc[j] = fmaf(vx, w[0], acc[j]);
                acc[j] = fmaf(vy, w[1], acc[j]);
            }
        }
        #pragma unroll
        for (int j = 0; j < 8; ++j) h2T[(j0 + j) * 64 + rr] = acc[j];
    }
    __syncthreads();

    {
        const int j0 = wave * 8;
        const int rr = lane;
        float h2v[32];
        #pragma unroll
        for (int k = 0; k < 32; ++k) h2v[k] = h2T[k * 64 + rr];
        float acc[8];
        #pragma unroll
        for (int j = 0; j < 8; ++j) acc[j] = b3[j0 + j];
        #pragma unroll
        for (int k = 0; k < 32; ++k) {
            const float pz = fmaxf(h2v[k], 0.f);
            const float mz = fmaxf(-h2v[k], 0.f);
            #pragma unroll
            for (int j = 0; j < 8; ++j) {
                const float* w = W3 + (size_t)(j0 + j) * 64;
                acc[j] = fmaf(pz, w[k],      acc[j]);
                acc[j] = fmaf(mz, w[32 + k], acc[j]);
            }
        }
        float o = 0.f;
        #pragma unroll
        for (int j = 0; j < 8; ++j) {
            const int jj = j0 + j;
            o = fmaf(fmaxf(acc[j], 0.f),  W4[jj],      o);
            o = fmaf(fmaxf(-acc[j], 0.f), W4[32 + jj], o);
        }
        obuf[wave][rr] = o;
    }
    __syncthreads();

    if (tid < 64) {
        const int row = row0 + tid;
        if (row < n)
            out[row] = obuf[0][tid] + obuf[1][tid] + obuf[2][tid] + obuf[3][tid];
    }
}

extern "C" void kernel_launch(void* const* d_in, const int* in_sizes, int n_in,
                              void* d_out, int out_size, void* d_ws, size_t ws_size,
                              hipStream_t stream) {
    const int*   x   = (const int*)  d_in[0];
    const float* emb = (const float*)d_in[1];
    const float* W2  = (const float*)d_in[2];
    const float* b2  = (const float*)d_in[3];
    const float* W3  = (const float*)d_in[4];
    const float* b3  = (const float*)d_in[5];
    const float* W4  = (const float*)d_in[6];
    float* out = (float*)d_out;
    const int n = out_size;                 // 131072 rows

    // workspace layout (16B-aligned sections)
    const size_t emb8_bytes = (size_t)7425 * 128;           // 950,400
    const size_t w2h_off    = emb8_bytes;                   // +8192
    const size_t w3h_off    = w2h_off + 8192;               // +4096
    const size_t slots_off  = w3h_off + 4096;               // +2048 (512 f32)
    const size_t amax_off   = slots_off + 2048;             // +16
    const size_t need       = amax_off + 16;

    if (ws_size >= need) {
        unsigned*     emb8  = (unsigned*)d_ws;
        _Float16*     W2h   = (_Float16*)((char*)d_ws + w2h_off);
        _Float16*     W3h   = (_Float16*)((char*)d_ws + w3h_off);
        float*        slots = (float*)((char*)d_ws + slots_off);
        float*        amaxp = (float*)((char*)d_ws + amax_off);
        const float4* emb4  = (const float4*)emb;

        const int n4 = 7424 * 32;   // 237,568 float4s
        hipLaunchKernelGGL(absmax_partial, dim3(NSLOTS), dim3(256), 0, stream,
                           emb4, slots, n4);

        const int nq = 7425 * 32;   // 237,600 u32s -> 929 blocks
        hipLaunchKernelGGL(prep_q8, dim3((nq + 255) / 256), dim3(256),
                           0, stream, emb4, emb8, W2, W3, W2h, W3h,
                           slots, amaxp);

        hipLaunchKernelGGL(nnue_q8, dim3((n + RPB - 1) / RPB), dim3(256),
                           0, stream, x, emb8, W2h, W3h, b2, b3, W4,
                           amaxp, out, n);
    } else {
        // legacy fallback: fp16 table + fp32-weight fused kernel
        __half2* emb16 = (__half2*)d_ws;
        const int npairs_real = 7424 * 64;
        const int npairs_tot  = 7425 * 64;
        hipLaunchKernelGGL(prep_fp16, dim3((npairs_tot + 255) / 256), dim3(256),
                           0, stream, emb, emb16, npairs_real, npairs_tot);
        hipLaunchKernelGGL(nnue_fused, dim3((n + RPB - 1) / RPB), dim3(256),
                           0, stream, x, (const __half*)emb16, W2, b2, W3, b3,
                           W4, out, n);
    }
}

// Round 6
// 120.500 us; speedup vs baseline: 3.4072x; 1.0015x over previous
//
#include <hip/hip_runtime.h>
#include <hip/hip_fp16.h>

// SilkNNUE R17 — explicit 2-row software-pipelined int8 gather.
//   R16 post-mortem: 52us is invariant across {fp16/int8, 128/64 CL,
//   29/10 DS-ops, 24/32 waves}. Instruction arithmetic: VALU ~9us at full
//   issue, L2 sectors ~27us => neither saturated. VGPR_Count=28 proves the
//   compiler kept only ONE row's loads in flight (no software pipelining
//   from #pragma unroll 4) => exposed L2 latency is the wall.
//   Fix: batch 2 training rows per gather iteration — all 16 idx ds_reads
//   + 16 global uint2 loads issued before any combine; row A combines
//   under row B's latency. VGPR ~50 fits __launch_bounds__(256,8) cap 64.
//   Chain (R16-verified): absmax_partial -> prep_q8 -> nnue_q8. No coop,
//   no atomics, no memset.

typedef _Float16 h2v_t  __attribute__((ext_vector_type(2)));
typedef _Float16 half8  __attribute__((ext_vector_type(8)));
typedef float    f32x4  __attribute__((ext_vector_type(4)));

constexpr int RPB    = 64;    // rows per block (main kernel)
constexpr int NSLOTS = 512;   // absmax partial slots

// ---- pass 1: per-block absmax partials (no init, no atomics) --------------
__global__ __launch_bounds__(256) void absmax_partial(
    const float4* __restrict__ emb4, float* __restrict__ slots, int n4)
{
    __shared__ float red[4];
    float m = 0.f;
    const int stride = NSLOTS * 256;
    for (int i = blockIdx.x * 256 + threadIdx.x; i < n4; i += stride) {
        float4 v = emb4[i];
        m = fmaxf(m, fmaxf(fmaxf(fabsf(v.x), fabsf(v.y)),
                           fmaxf(fabsf(v.z), fabsf(v.w))));
    }
    #pragma unroll
    for (int s = 1; s < 64; s <<= 1)
        m = fmaxf(m, __shfl_xor(m, s));
    if ((threadIdx.x & 63) == 0) red[threadIdx.x >> 6] = m;
    __syncthreads();
    if (threadIdx.x == 0)
        slots[blockIdx.x] = fmaxf(fmaxf(red[0], red[1]), fmaxf(red[2], red[3]));
}

// ---- pass 2: reduce slots + quantize emb -> u8 + W2/W3 -> fp16 ------------
__global__ __launch_bounds__(256) void prep_q8(
    const float4* __restrict__ emb4, unsigned* __restrict__ emb8,
    const float* __restrict__ W2, const float* __restrict__ W3,
    _Float16* __restrict__ W2h, _Float16* __restrict__ W3h,
    const float* __restrict__ slots, float* __restrict__ amax_out)
{
    __shared__ float red[4];
    const int tid = threadIdx.x;
    // block-local reduce of the 512 partials (2KB, L2-hot)
    float m = fmaxf(slots[tid], slots[tid + 256]);
    #pragma unroll
    for (int s = 1; s < 64; s <<= 1)
        m = fmaxf(m, __shfl_xor(m, s));
    if ((tid & 63) == 0) red[tid >> 6] = m;
    __syncthreads();
    const float amax = fmaxf(fmaxf(fmaxf(red[0], red[1]),
                                   fmaxf(red[2], red[3])), 1e-20f);
    const float qs = 127.f / amax;

    const int i = blockIdx.x * 256 + tid;
    if (i == 0) *amax_out = amax;
    if (i < 7425 * 32) {
        unsigned w = 0x80808080u;              // zero row 7424: q=0
        if (i < 7424 * 32) {
            float4 v = emb4[i];
            int q0 = min(127, max(-127, (int)rintf(v.x * qs)));
            int q1 = min(127, max(-127, (int)rintf(v.y * qs)));
            int q2 = min(127, max(-127, (int)rintf(v.z * qs)));
            int q3 = min(127, max(-127, (int)rintf(v.w * qs)));
            // byte order (d0,d2,d1,d3): lo-mask slots = dims (4j,4j+1),
            // hi-perm slots = dims (4j+2,4j+3)
            w = (unsigned)(q0 + 128)
              | ((unsigned)(q2 + 128) << 8)
              | ((unsigned)(q1 + 128) << 16)
              | ((unsigned)(q3 + 128) << 24);
        }
        emb8[i] = w;
    }
    if (i < 4096) W2h[i] = (_Float16)W2[i];
    if (i < 2048) W3h[i] = (_Float16)W3[i];
}

__device__ inline unsigned cvt_pair(unsigned w, float sc, float cb) {
    float f0 = (float)(w & 0xffffu) * sc + cb;
    float f1 = (float)(w >> 16)     * sc + cb;
    h2v_t h;
    h[0] = (_Float16)fmaxf(f0, 0.f);
    h[1] = (_Float16)fmaxf(f1, 0.f);
    return __builtin_bit_cast(unsigned, h);
}

// ---------------- fused kernel (int8 gather, 2-row pipelined) --------------
__global__ __launch_bounds__(256, 8) void nnue_q8(
    const int*      __restrict__ x,      // (N,32)
    const unsigned* __restrict__ emb8,   // (7425,128) u8 permuted
    const _Float16* __restrict__ W2h,    // (32,128) fp16
    const _Float16* __restrict__ W3h,    // (32,64) fp16
    const float*    __restrict__ b2,
    const float*    __restrict__ b3,
    const float*    __restrict__ W4,     // (64,)
    const float*    __restrict__ amaxp,
    float*          __restrict__ out, int n)
{
    // per-wave: hT = 16 rows x 16 uint4 (swizzled), later aliased by a2 tile
    __shared__ __align__(16) char hmem[4][4096];   // 16384 B
    // per-wave packed u16 indices
    __shared__ __align__(16) char xmem[4][1024];   //  4096 B  (total 20480)

    const int tid  = threadIdx.x;
    const int lane = tid & 63;
    const int wave = tid >> 6;
    const int row0 = blockIdx.x * RPB;
    const int wrow0 = __builtin_amdgcn_readfirstlane(row0 + wave * 16);

    const float amax = *amaxp;
    const float sc = amax * (1.f / 127.f);
    const float cb = -4096.f * sc;      // bias removal: 32 features x 128

    const int g   = lane >> 4;          // feature subgroup 0..3
    const int sub = lane & 15;          // 8B sub-packet of 128B int8 row
    const unsigned subOff = (unsigned)sub * 8u;
    const char* embb = (const char*)emb8;

    unsigned short* xw = (unsigned short*)&xmem[wave][0];

    // ---- stage indices packed u16 (features 29..31 -> zero row 7424) ------
    {
        const int4* xb = (const int4*)(x + (size_t)wrow0 * 32);
        int4 a = xb[lane * 2];
        int4 b = xb[lane * 2 + 1];
        if ((lane & 3) == 3) { b.y = 7424; b.z = 7424; b.w = 7424; }
        uint4 pk;
        pk.x = ((unsigned)a.x & 0xffffu) | ((unsigned)a.y << 16);
        pk.y = ((unsigned)a.z & 0xffffu) | ((unsigned)a.w << 16);
        pk.z = ((unsigned)b.x & 0xffffu) | ((unsigned)b.y << 16);
        pk.w = ((unsigned)b.z & 0xffffu) | ((unsigned)b.w << 16);
        ((uint4*)xw)[lane] = pk;
    }
    // same-wave DS ordering; no barriers anywhere in this kernel.

    // ---- gather: 2 rows per iter, 16 loads in flight, 16-bit-slot adds ----
    #pragma unroll 2
    for (int rb = 0; rb < 16; rb += 2) {
        const unsigned short* xrowA = xw + rb * 32 + g;
        const unsigned short* xrowB = xw + (rb + 1) * 32 + g;
        uint2 va[8], vb[8];
        #pragma unroll
        for (int b = 0; b < 8; ++b) {
            const unsigned ia = xrowA[4 * b];        // ds_read_u16 bcast
            const unsigned ib = xrowB[4 * b];
            va[b] = *(const uint2*)(embb + ((ia << 7) + subOff));
            vb[b] = *(const uint2*)(embb + ((ib << 7) + subOff));
        }
        // ---- combine row A (under row B's in-flight loads) ----
        {
            unsigned aL0 = 0, aH0 = 0, aL1 = 0, aH1 = 0;
            #pragma unroll
            for (int b = 0; b < 8; ++b) {
                aL0 += va[b].x & 0x00ff00ffu;
                aH0 += __builtin_amdgcn_perm(0u, va[b].x, 0x0c030c01u);
                aL1 += va[b].y & 0x00ff00ffu;
                aH1 += __builtin_amdgcn_perm(0u, va[b].y, 0x0c030c01u);
            }
            aL0 += (unsigned)__shfl_xor((int)aL0, 16);
            aL0 += (unsigned)__shfl_xor((int)aL0, 32);
            aH0 += (unsigned)__shfl_xor((int)aH0, 16);
            aH0 += (unsigned)__shfl_xor((int)aH0, 32);
            aL1 += (unsigned)__shfl_xor((int)aL1, 16);
            aL1 += (unsigned)__shfl_xor((int)aL1, 32);
            aH1 += (unsigned)__shfl_xor((int)aH1, 16);
            aH1 += (unsigned)__shfl_xor((int)aH1, 32);
            if (g == 0) {
                uint4 o;
                o.x = cvt_pair(aL0, sc, cb);
                o.y = cvt_pair(aH0, sc, cb);
                o.z = cvt_pair(aL1, sc, cb);
                o.w = cvt_pair(aH1, sc, cb);
                ((uint4*)&hmem[wave][0])[rb * 16 + (sub ^ (rb & 7))] = o;
            }
        }
        // ---- combine row B ----
        {
            unsigned aL0 = 0, aH0 = 0, aL1 = 0, aH1 = 0;
            #pragma unroll
            for (int b = 0; b < 8; ++b) {
                aL0 += vb[b].x & 0x00ff00ffu;
                aH0 += __builtin_amdgcn_perm(0u, vb[b].x, 0x0c030c01u);
                aL1 += vb[b].y & 0x00ff00ffu;
                aH1 += __builtin_amdgcn_perm(0u, vb[b].y, 0x0c030c01u);
            }
            aL0 += (unsigned)__shfl_xor((int)aL0, 16);
            aL0 += (unsigned)__shfl_xor((int)aL0, 32);
            aH0 += (unsigned)__shfl_xor((int)aH0, 16);
            aH0 += (unsigned)__shfl_xor((int)aH0, 32);
            aL1 += (unsigned)__shfl_xor((int)aL1, 16);
            aL1 += (unsigned)__shfl_xor((int)aL1, 32);
            aH1 += (unsigned)__shfl_xor((int)aH1, 16);
            aH1 += (unsigned)__shfl_xor((int)aH1, 32);
            if (g == 0) {
                const int r = rb + 1;
                uint4 o;
                o.x = cvt_pair(aL0, sc, cb);
                o.y = cvt_pair(aH0, sc, cb);
                o.z = cvt_pair(aL1, sc, cb);
                o.w = cvt_pair(aH1, sc, cb);
                ((uint4*)&hmem[wave][0])[r * 16 + (sub ^ (r & 7))] = o;
            }
        }
    }

    // ================= dense (per-wave MFMA, same wave's 16 rows) ==========
    const uint4* hT = (const uint4*)&hmem[wave][0];
    const int q  = lane >> 4;     // k-quad
    const int nn = lane & 15;     // A row m / B col n / C col n

    half8 bw2[2][4];
    #pragma unroll
    for (int nt = 0; nt < 2; ++nt)
        #pragma unroll
        for (int kk = 0; kk < 4; ++kk)
            bw2[nt][kk] = __builtin_bit_cast(half8,
                *(const uint4*)((const char*)W2h +
                    ((nt * 16 + nn) * 128 + kk * 32 + q * 8) * 2));

    half8 af[4];
    #pragma unroll
    for (int kk = 0; kk < 4; ++kk)
        af[kk] = __builtin_bit_cast(half8,
            hT[nn * 16 + ((4 * kk + q) ^ (nn & 7))]);

    f32x4 acc0 = {0.f, 0.f, 0.f, 0.f}, acc1 = {0.f, 0.f, 0.f, 0.f};
    #pragma unroll
    for (int kk = 0; kk < 4; ++kk) {
        acc0 = __builtin_amdgcn_mfma_f32_16x16x32_f16(af[kk], bw2[0][kk], acc0, 0, 0, 0);
        acc1 = __builtin_amdgcn_mfma_f32_16x16x32_f16(af[kk], bw2[1][kk], acc1, 0, 0, 0);
    }
    const float bb0 = b2[nn], bb1 = b2[16 + nn];

    // CReLU + transpose via LDS (stride 68 halfs). a2 aliases hT:
    // all hT (af) reads completed above, same-wave program order.
    _Float16* a2 = (_Float16*)&hmem[wave][0];
    #pragma unroll
    for (int r = 0; r < 4; ++r) {
        const float v0 = acc0[r] + bb0;
        const float v1 = acc1[r] + bb1;
        const int m = q * 4 + r;
        a2[m * 68 + nn]      = (_Float16)fmaxf(v0, 0.f);
        a2[m * 68 + 16 + nn] = (_Float16)fmaxf(v1, 0.f);
        a2[m * 68 + 32 + nn] = (_Float16)fmaxf(-v0, 0.f);
        a2[m * 68 + 48 + nn] = (_Float16)fmaxf(-v1, 0.f);
    }

    half8 bw3[2][2];
    #pragma unroll
    for (int nt = 0; nt < 2; ++nt)
        #pragma unroll
        for (int kk = 0; kk < 2; ++kk)
            bw3[nt][kk] = __builtin_bit_cast(half8,
                *(const uint4*)((const char*)W3h +
                    ((nt * 16 + nn) * 64 + kk * 32 + q * 8) * 2));

    half8 a2f[2];
    #pragma unroll
    for (int kk = 0; kk < 2; ++kk) {
        const _Float16* pp = &a2[nn * 68 + kk * 32 + q * 8];
        half8 t;
        #pragma unroll
        for (int j = 0; j < 8; ++j) t[j] = pp[j];
        a2f[kk] = t;
    }

    f32x4 acc30 = {0.f, 0.f, 0.f, 0.f}, acc31 = {0.f, 0.f, 0.f, 0.f};
    #pragma unroll
    for (int kk = 0; kk < 2; ++kk) {
        acc30 = __builtin_amdgcn_mfma_f32_16x16x32_f16(a2f[kk], bw3[0][kk], acc30, 0, 0, 0);
        acc31 = __builtin_amdgcn_mfma_f32_16x16x32_f16(a2f[kk], bw3[1][kk], acc31, 0, 0, 0);
    }
    const float bb30 = b3[nn], bb31 = b3[16 + nn];

    const float w4a = W4[nn],      w4b = W4[16 + nn];
    const float w4c = W4[32 + nn], w4d = W4[48 + nn];
    float o[4];
    #pragma unroll
    for (int r = 0; r < 4; ++r) {
        const float v0 = acc30[r] + bb30;
        const float v1 = acc31[r] + bb31;
        o[r] = fmaxf(v0, 0.f) * w4a + fmaxf(-v0, 0.f) * w4c
             + fmaxf(v1, 0.f) * w4b + fmaxf(-v1, 0.f) * w4d;
    }
    #pragma unroll
    for (int s = 1; s < 16; s <<= 1) {
        #pragma unroll
        for (int r = 0; r < 4; ++r) o[r] += __shfl_xor(o[r], s);
    }
    if (nn == 0) {
        #pragma unroll
        for (int r = 0; r < 4; ++r) {
            const int row = wrow0 + q * 4 + r;
            if (row < n) out[row] = o[r];
        }
    }
}

// ---------------- fallback (fp16 table + fp32-weight fused) ----------------
__global__ __launch_bounds__(256) void prep_fp16(
    const float* __restrict__ emb, __half2* __restrict__ emb16,
    int npairs_real, int npairs_tot)
{
    int i = blockIdx.x * blockDim.x + threadIdx.x;
    if (i < npairs_tot) {
        float2 v = make_float2(0.f, 0.f);
        if (i < npairs_real) v = ((const float2*)emb)[i];
        emb16[i] = __floats2half2_rn(v.x, v.y);
    }
}

__global__ __launch_bounds__(256) void nnue_fused(
    const int*    __restrict__ x,
    const __half* __restrict__ emb16,
    const float*  __restrict__ W2, const float* __restrict__ b2,
    const float*  __restrict__ W3, const float* __restrict__ b3,
    const float*  __restrict__ W4,
    float*        __restrict__ out, int n)
{
    __shared__ int     xlds[4][512];
    __shared__ __half2 hbuf[64][65];
    __shared__ float   h2T[32 * 64];
    __shared__ float   obuf[4][64];

    const int tid  = threadIdx.x;
    const int lane = tid & 63;
    const int wave = tid >> 6;
    const int row0 = blockIdx.x * RPB;
    const int wrow0 = __builtin_amdgcn_readfirstlane(row0 + wave * 16);
    const int g   = lane >> 4;
    const int sub = lane & 15;
    const unsigned subOff = (unsigned)sub * 16u;

    {
        const int4* xb = (const int4*)(x + (size_t)wrow0 * 32);
        int4 a = xb[lane * 2];
        int4 b = xb[lane * 2 + 1];
        if ((lane & 3) == 3) { b.y = 7424; b.z = 7424; b.w = 7424; }
        ((int4*)&xlds[wave][0])[lane * 2]     = a;
        ((int4*)&xlds[wave][0])[lane * 2 + 1] = b;
    }

    #pragma unroll 4
    for (int r = 0; r < 16; ++r) {
        const int* xrow = &xlds[wave][r * 32 + g];
        uint4 v[8];
        #pragma unroll
        for (int b = 0; b < 8; ++b) {
            const int idx = xrow[4 * b];
            const unsigned off = ((unsigned)idx << 8) + subOff;
            v[b] = *(const uint4*)((const char*)emb16 + off);
        }
        h2v_t hacc[4];
        #pragma unroll
        for (int q = 0; q < 4; ++q) hacc[q] = (h2v_t)0;
        #pragma unroll
        for (int b = 0; b < 8; ++b) {
            hacc[0] += __builtin_bit_cast(h2v_t, v[b].x);
            hacc[1] += __builtin_bit_cast(h2v_t, v[b].y);
            hacc[2] += __builtin_bit_cast(h2v_t, v[b].z);
            hacc[3] += __builtin_bit_cast(h2v_t, v[b].w);
        }
        #pragma unroll
        for (int q = 0; q < 4; ++q) {
            unsigned u = __builtin_bit_cast(unsigned, hacc[q]);
            h2v_t t = __builtin_bit_cast(h2v_t, u);
            t += __builtin_bit_cast(h2v_t, (unsigned)__shfl_xor((int)u, 16));
            unsigned u2 = __builtin_bit_cast(unsigned, t);
            t += __builtin_bit_cast(h2v_t, (unsigned)__shfl_xor((int)u2, 32));
            hacc[q] = __builtin_elementwise_max(t, (h2v_t)0);
        }
        if (g == 0) {
            const int row = wave * 16 + r;
            #pragma unroll
            for (int q = 0; q < 4; ++q)
                hbuf[row][sub * 4 + q] = __builtin_bit_cast(__half2, hacc[q]);
        }
    }
    __syncthreads();

    {
        const int j0 = wave * 8;
        const int rr = lane;
        float acc[8];
        #pragma unroll
        for (int j = 0; j < 8; ++j) acc[j] = b2[j0 + j];
        #pragma unroll
        for (int d2 = 0; d2 < 64; ++d2) {
            const __half2 hv = hbuf[rr][d2];
            const float vx = __low2float(hv), vy = __high2float(hv);
            #pragma unroll
            for (int j = 0; j < 8; ++j) {
                const float* w = W2 + (size_t)(j0 + j) * 128 + d2 * 2;
                acc[j] = fmaf(vx, w[0], acc[j]);
                acc[j] = fmaf(vy, w[1], acc[j]);
            }
        }
        #pragma unroll
        for (int j = 0; j < 8; ++j) h2T[(j0 + j) * 64 + rr] = acc[j];
    }
    __syncthreads();

    {
        const int j0 = wave * 8;
        const int rr = lane;
        float h2v[32];
        #pragma unroll
        for (int k = 0; k < 32; ++k) h2v[k] = h2T[k * 64 + rr];
        float acc[8];
        #pragma unroll
        for (int j = 0; j < 8; ++j) acc[j] = b3[j0 + j];
        #pragma unroll
        for (int k = 0; k < 32; ++k) {
            const float pz = fmaxf(h2v[k], 0.f);
            const float mz = fmaxf(-h2v[k], 0.f);
            #pragma unroll
            for (int j = 0; j < 8; ++j) {
                const float* w = W3 + (size_t)(j0 + j) * 64;
                acc[j] = fmaf(pz, w[k],      acc[j]);
                acc[j] = fmaf(mz, w[32 + k], acc[j]);
            }
        }
        float o = 0.f;
        #pragma unroll
        for (int j = 0; j < 8; ++j) {
            const int jj = j0 + j;
            o = fmaf(fmaxf(acc[j], 0.f),  W4[jj],      o);
            o = fmaf(fmaxf(-acc[j], 0.f), W4[32 + jj], o);
        }
        obuf[wave][rr] = o;
    }
    __syncthreads();

    if (tid < 64) {
        const int row = row0 + tid;
        if (row < n)
            out[row] = obuf[0][tid] + obuf[1][tid] + obuf[2][tid] + obuf[3][tid];
    }
}

extern "C" void kernel_launch(void* const* d_in, const int* in_sizes, int n_in,
                              void* d_out, int out_size, void* d_ws, size_t ws_size,
                              hipStream_t stream) {
    const int*   x   = (const int*)  d_in[0];
    const float* emb = (const float*)d_in[1];
    const float* W2  = (const float*)d_in[2];
    const float* b2  = (const float*)d_in[3];
    const float* W3  = (const float*)d_in[4];
    const float* b3  = (const float*)d_in[5];
    const float* W4  = (const float*)d_in[6];
    float* out = (float*)d_out;
    const int n = out_size;                 // 131072 rows

    // workspace layout (16B-aligned sections)
    const size_t emb8_bytes = (size_t)7425 * 128;           // 950,400
    const size_t w2h_off    = emb8_bytes;                   // +8192
    const size_t w3h_off    = w2h_off + 8192;               // +4096
    const size_t slots_off  = w3h_off + 4096;               // +2048 (512 f32)
    const size_t amax_off   = slots_off + 2048;             // +16
    const size_t need       = amax_off + 16;

    if (ws_size >= need) {
        unsigned*     emb8  = (unsigned*)d_ws;
        _Float16*     W2h   = (_Float16*)((char*)d_ws + w2h_off);
        _Float16*     W3h   = (_Float16*)((char*)d_ws + w3h_off);
        float*        slots = (float*)((char*)d_ws + slots_off);
        float*        amaxp = (float*)((char*)d_ws + amax_off);
        const float4* emb4  = (const float4*)emb;

        const int n4 = 7424 * 32;   // 237,568 float4s
        hipLaunchKernelGGL(absmax_partial, dim3(NSLOTS), dim3(256), 0, stream,
                           emb4, slots, n4);

        const int nq = 7425 * 32;   // 237,600 u32s -> 929 blocks
        hipLaunchKernelGGL(prep_q8, dim3((nq + 255) / 256), dim3(256),
                           0, stream, emb4, emb8, W2, W3, W2h, W3h,
                           slots, amaxp);

        hipLaunchKernelGGL(nnue_q8, dim3((n + RPB - 1) / RPB), dim3(256),
                           0, stream, x, emb8, W2h, W3h, b2, b3, W4,
                           amaxp, out, n);
    } else {
        // legacy fallback: fp16 table + fp32-weight fused kernel
        __half2* emb16 = (__half2*)d_ws;
        const int npairs_real = 7424 * 64;
        const int npairs_tot  = 7425 * 64;
        hipLaunchKernelGGL(prep_fp16, dim3((npairs_tot + 255) / 256), dim3(256),
                           0, stream, emb, emb16, npairs_real, npairs_tot);
        hipLaunchKernelGGL(nnue_fused, dim3((n + RPB - 1) / RPB), dim3(256),
                           0, stream, x, (const __half*)emb16, W2, b2, W3, b3,
                           W4, out, n);
    }
}

// Round 7
// 120.100 us; speedup vs baseline: 3.4185x; 1.0033x over previous
//
#include <hip/hip_runtime.h>
#include <hip/hip_fp16.h>

// SilkNNUE R18 — reduce-scatter butterfly: full-lane convert + store.
//   R17 null (VGPR 32: compiler re-serialized the 2-row pipeline).
//   Counter decomposition: 41% VALUBusy = ~21us of the 52; inner loop was
//   ~174 VALU/row-iter with the cvt block (~80 slots) at 25% lane use and
//   an 8-shfl all-to-one butterfly.
//   Fix: 2-level reduce-SCATTER (xor32 keep-half, xor16 keep-half): 6 shfl
//   + 6 add + 3 cndmask, after which EVERY lane holds one summed u32 =
//   fp16-word w = 4*sub+g of row r. One cvt_pair at full lane util; store
//   is full-wave ds_write_b32 at r*256 + ((sub^(r&7))<<4) + 4g (2-way
//   banked = free). ~96 VALU/row-iter. Gather loads/addressing, chain
//   (absmax_partial -> prep_q8 -> nnue_q8), dense MFMA: R16-verified,
//   unchanged.

typedef _Float16 h2v_t  __attribute__((ext_vector_type(2)));
typedef _Float16 half8  __attribute__((ext_vector_type(8)));
typedef float    f32x4  __attribute__((ext_vector_type(4)));

constexpr int RPB    = 64;    // rows per block (main kernel)
constexpr int NSLOTS = 512;   // absmax partial slots

// ---- pass 1: per-block absmax partials (no init, no atomics) --------------
__global__ __launch_bounds__(256) void absmax_partial(
    const float4* __restrict__ emb4, float* __restrict__ slots, int n4)
{
    __shared__ float red[4];
    float m = 0.f;
    const int stride = NSLOTS * 256;
    for (int i = blockIdx.x * 256 + threadIdx.x; i < n4; i += stride) {
        float4 v = emb4[i];
        m = fmaxf(m, fmaxf(fmaxf(fabsf(v.x), fabsf(v.y)),
                           fmaxf(fabsf(v.z), fabsf(v.w))));
    }
    #pragma unroll
    for (int s = 1; s < 64; s <<= 1)
        m = fmaxf(m, __shfl_xor(m, s));
    if ((threadIdx.x & 63) == 0) red[threadIdx.x >> 6] = m;
    __syncthreads();
    if (threadIdx.x == 0)
        slots[blockIdx.x] = fmaxf(fmaxf(red[0], red[1]), fmaxf(red[2], red[3]));
}

// ---- pass 2: reduce slots + quantize emb -> u8 + W2/W3 -> fp16 ------------
__global__ __launch_bounds__(256) void prep_q8(
    const float4* __restrict__ emb4, unsigned* __restrict__ emb8,
    const float* __restrict__ W2, const float* __restrict__ W3,
    _Float16* __restrict__ W2h, _Float16* __restrict__ W3h,
    const float* __restrict__ slots, float* __restrict__ amax_out)
{
    __shared__ float red[4];
    const int tid = threadIdx.x;
    // block-local reduce of the 512 partials (2KB, L2-hot)
    float m = fmaxf(slots[tid], slots[tid + 256]);
    #pragma unroll
    for (int s = 1; s < 64; s <<= 1)
        m = fmaxf(m, __shfl_xor(m, s));
    if ((tid & 63) == 0) red[tid >> 6] = m;
    __syncthreads();
    const float amax = fmaxf(fmaxf(fmaxf(red[0], red[1]),
                                   fmaxf(red[2], red[3])), 1e-20f);
    const float qs = 127.f / amax;

    const int i = blockIdx.x * 256 + tid;
    if (i == 0) *amax_out = amax;
    if (i < 7425 * 32) {
        unsigned w = 0x80808080u;              // zero row 7424: q=0
        if (i < 7424 * 32) {
            float4 v = emb4[i];
            int q0 = min(127, max(-127, (int)rintf(v.x * qs)));
            int q1 = min(127, max(-127, (int)rintf(v.y * qs)));
            int q2 = min(127, max(-127, (int)rintf(v.z * qs)));
            int q3 = min(127, max(-127, (int)rintf(v.w * qs)));
            // byte order (d0,d2,d1,d3): lo-mask slots = dims (4j,4j+1),
            // hi-perm slots = dims (4j+2,4j+3)
            w = (unsigned)(q0 + 128)
              | ((unsigned)(q2 + 128) << 8)
              | ((unsigned)(q1 + 128) << 16)
              | ((unsigned)(q3 + 128) << 24);
        }
        emb8[i] = w;
    }
    if (i < 4096) W2h[i] = (_Float16)W2[i];
    if (i < 2048) W3h[i] = (_Float16)W3[i];
}

__device__ inline unsigned cvt_pair(unsigned w, float sc, float cb) {
    float f0 = (float)(w & 0xffffu) * sc + cb;
    float f1 = (float)(w >> 16)     * sc + cb;
    h2v_t h;
    h[0] = (_Float16)fmaxf(f0, 0.f);
    h[1] = (_Float16)fmaxf(f1, 0.f);
    return __builtin_bit_cast(unsigned, h);
}

// ---------------- fused kernel (int8 gather, reduce-scatter) ---------------
__global__ __launch_bounds__(256, 8) void nnue_q8(
    const int*      __restrict__ x,      // (N,32)
    const unsigned* __restrict__ emb8,   // (7425,128) u8 permuted
    const _Float16* __restrict__ W2h,    // (32,128) fp16
    const _Float16* __restrict__ W3h,    // (32,64) fp16
    const float*    __restrict__ b2,
    const float*    __restrict__ b3,
    const float*    __restrict__ W4,     // (64,)
    const float*    __restrict__ amaxp,
    float*          __restrict__ out, int n)
{
    // per-wave: hT = 16 rows x 16 uint4 (swizzled), later aliased by a2 tile
    __shared__ __align__(16) char hmem[4][4096];   // 16384 B
    // per-wave packed u16 indices
    __shared__ __align__(16) char xmem[4][1024];   //  4096 B  (total 20480)

    const int tid  = threadIdx.x;
    const int lane = tid & 63;
    const int wave = tid >> 6;
    const int row0 = blockIdx.x * RPB;
    const int wrow0 = __builtin_amdgcn_readfirstlane(row0 + wave * 16);

    const float amax = *amaxp;
    const float sc = amax * (1.f / 127.f);
    const float cb = -4096.f * sc;      // bias removal: 32 features x 128

    const int g   = lane >> 4;          // feature subgroup 0..3
    const int sub = lane & 15;          // 8B sub-packet of 128B int8 row
    const unsigned subOff = (unsigned)sub * 8u;
    const char* embb = (const char*)emb8;

    unsigned short* xw = (unsigned short*)&xmem[wave][0];

    // ---- stage indices packed u16 (features 29..31 -> zero row 7424) ------
    {
        const int4* xb = (const int4*)(x + (size_t)wrow0 * 32);
        int4 a = xb[lane * 2];
        int4 b = xb[lane * 2 + 1];
        if ((lane & 3) == 3) { b.y = 7424; b.z = 7424; b.w = 7424; }
        uint4 pk;
        pk.x = ((unsigned)a.x & 0xffffu) | ((unsigned)a.y << 16);
        pk.y = ((unsigned)a.z & 0xffffu) | ((unsigned)a.w << 16);
        pk.z = ((unsigned)b.x & 0xffffu) | ((unsigned)b.y << 16);
        pk.w = ((unsigned)b.z & 0xffffu) | ((unsigned)b.w << 16);
        ((uint4*)xw)[lane] = pk;
    }
    // same-wave DS ordering; no barriers anywhere in this kernel.

    // lane (g,sub) finally owns fp16-word w = 4*sub+g of each row
    const int wIdx = 4 * sub + g;

    // ---- gather: 8 x uint2 per row, reduce-scatter, full-lane cvt+store ---
    #pragma unroll 4
    for (int r = 0; r < 16; ++r) {
        const unsigned short* xrow = xw + r * 32 + g;
        uint2 v[8];
        #pragma unroll
        for (int b = 0; b < 8; ++b) {
            const unsigned idx = xrow[4 * b];        // ds_read_u16 bcast
            v[b] = *(const uint2*)(embb + ((idx << 7) + subOff));
        }
        // accumulate 8 features into 4 accs (16-bit slots, max 8160, exact)
        unsigned aL0 = 0, aH0 = 0, aL1 = 0, aH1 = 0;
        #pragma unroll
        for (int b = 0; b < 8; ++b) {
            aL0 += v[b].x & 0x00ff00ffu;
            aH0 += __builtin_amdgcn_perm(0u, v[b].x, 0x0c030c01u);
            aL1 += v[b].y & 0x00ff00ffu;
            aH1 += __builtin_amdgcn_perm(0u, v[b].y, 0x0c030c01u);
        }
        // reduce-scatter over g (lane bits 4,5): level 1 keeps 2 accs,
        // level 2 keeps 1. Exact u32 adds.
        //   g=0 -> sum(aL0)=dims(8s,8s+1)   g=1 -> sum(aH0)=dims(8s+2,8s+3)
        //   g=2 -> sum(aL1)=dims(8s+4,8s+5) g=3 -> sum(aH1)=dims(8s+6,8s+7)
        const unsigned tA = (unsigned)__shfl_xor((int)aL0, 32);
        const unsigned tB = (unsigned)__shfl_xor((int)aH0, 32);
        const unsigned tC = (unsigned)__shfl_xor((int)aL1, 32);
        const unsigned tD = (unsigned)__shfl_xor((int)aH1, 32);
        const bool glo = (g < 2);
        const unsigned X = glo ? (aL0 + tA) : (aL1 + tC);
        const unsigned Y = glo ? (aH0 + tB) : (aH1 + tD);
        const unsigned tX = (unsigned)__shfl_xor((int)X, 16);
        const unsigned tY = (unsigned)__shfl_xor((int)Y, 16);
        const unsigned Z = ((g & 1) == 0) ? (X + tX) : (Y + tY);
        // full-wave store: word wIdx of row r, swizzled granule
        const int byteOff = r * 256 + ((sub ^ (r & 7)) << 4) + 4 * g;
        *(unsigned*)(&hmem[wave][byteOff]) = cvt_pair(Z, sc, cb);
    }

    // ================= dense (per-wave MFMA, same wave's 16 rows) ==========
    const uint4* hT = (const uint4*)&hmem[wave][0];
    const int q  = lane >> 4;     // k-quad
    const int nn = lane & 15;     // A row m / B col n / C col n

    half8 bw2[2][4];
    #pragma unroll
    for (int nt = 0; nt < 2; ++nt)
        #pragma unroll
        for (int kk = 0; kk < 4; ++kk)
            bw2[nt][kk] = __builtin_bit_cast(half8,
                *(const uint4*)((const char*)W2h +
                    ((nt * 16 + nn) * 128 + kk * 32 + q * 8) * 2));

    half8 af[4];
    #pragma unroll
    for (int kk = 0; kk < 4; ++kk)
        af[kk] = __builtin_bit_cast(half8,
            hT[nn * 16 + ((4 * kk + q) ^ (nn & 7))]);

    f32x4 acc0 = {0.f, 0.f, 0.f, 0.f}, acc1 = {0.f, 0.f, 0.f, 0.f};
    #pragma unroll
    for (int kk = 0; kk < 4; ++kk) {
        acc0 = __builtin_amdgcn_mfma_f32_16x16x32_f16(af[kk], bw2[0][kk], acc0, 0, 0, 0);
        acc1 = __builtin_amdgcn_mfma_f32_16x16x32_f16(af[kk], bw2[1][kk], acc1, 0, 0, 0);
    }
    const float bb0 = b2[nn], bb1 = b2[16 + nn];

    // CReLU + transpose via LDS (stride 68 halfs). a2 aliases hT:
    // all hT (af) reads completed above, same-wave program order.
    _Float16* a2 = (_Float16*)&hmem[wave][0];
    #pragma unroll
    for (int r = 0; r < 4; ++r) {
        const float v0 = acc0[r] + bb0;
        const float v1 = acc1[r] + bb1;
        const int m = q * 4 + r;
        a2[m * 68 + nn]      = (_Float16)fmaxf(v0, 0.f);
        a2[m * 68 + 16 + nn] = (_Float16)fmaxf(v1, 0.f);
        a2[m * 68 + 32 + nn] = (_Float16)fmaxf(-v0, 0.f);
        a2[m * 68 + 48 + nn] = (_Float16)fmaxf(-v1, 0.f);
    }

    half8 bw3[2][2];
    #pragma unroll
    for (int nt = 0; nt < 2; ++nt)
        #pragma unroll
        for (int kk = 0; kk < 2; ++kk)
            bw3[nt][kk] = __builtin_bit_cast(half8,
                *(const uint4*)((const char*)W3h +
                    ((nt * 16 + nn) * 64 + kk * 32 + q * 8) * 2));

    half8 a2f[2];
    #pragma unroll
    for (int kk = 0; kk < 2; ++kk) {
        const _Float16* pp = &a2[nn * 68 + kk * 32 + q * 8];
        half8 t;
        #pragma unroll
        for (int j = 0; j < 8; ++j) t[j] = pp[j];
        a2f[kk] = t;
    }

    f32x4 acc30 = {0.f, 0.f, 0.f, 0.f}, acc31 = {0.f, 0.f, 0.f, 0.f};
    #pragma unroll
    for (int kk = 0; kk < 2; ++kk) {
        acc30 = __builtin_amdgcn_mfma_f32_16x16x32_f16(a2f[kk], bw3[0][kk], acc30, 0, 0, 0);
        acc31 = __builtin_amdgcn_mfma_f32_16x16x32_f16(a2f[kk], bw3[1][kk], acc31, 0, 0, 0);
    }
    const float bb30 = b3[nn], bb31 = b3[16 + nn];

    const float w4a = W4[nn],      w4b = W4[16 + nn];
    const float w4c = W4[32 + nn], w4d = W4[48 + nn];
    float o[4];
    #pragma unroll
    for (int r = 0; r < 4; ++r) {
        const float v0 = acc30[r] + bb30;
        const float v1 = acc31[r] + bb31;
        o[r] = fmaxf(v0, 0.f) * w4a + fmaxf(-v0, 0.f) * w4c
             + fmaxf(v1, 0.f) * w4b + fmaxf(-v1, 0.f) * w4d;
    }
    #pragma unroll
    for (int s = 1; s < 16; s <<= 1) {
        #pragma unroll
        for (int r = 0; r < 4; ++r) o[r] += __shfl_xor(o[r], s);
    }
    if (nn == 0) {
        #pragma unroll
        for (int r = 0; r < 4; ++r) {
            const int row = wrow0 + q * 4 + r;
            if (row < n) out[row] = o[r];
        }
    }
}

// ---------------- fallback (fp16 table + fp32-weight fused) ----------------
__global__ __launch_bounds__(256) void prep_fp16(
    const float* __restrict__ emb, __half2* __restrict__ emb16,
    int npairs_real, int npairs_tot)
{
    int i = blockIdx.x * blockDim.x + threadIdx.x;
    if (i < npairs_tot) {
        float2 v = make_float2(0.f, 0.f);
        if (i < npairs_real) v = ((const float2*)emb)[i];
        emb16[i] = __floats2half2_rn(v.x, v.y);
    }
}

__global__ __launch_bounds__(256) void nnue_fused(
    const int*    __restrict__ x,
    const __half* __restrict__ emb16,
    const float*  __restrict__ W2, const float* __restrict__ b2,
    const float*  __restrict__ W3, const float* __restrict__ b3,
    const float*  __restrict__ W4,
    float*        __restrict__ out, int n)
{
    __shared__ int     xlds[4][512];
    __shared__ __half2 hbuf[64][65];
    __shared__ float   h2T[32 * 64];
    __shared__ float   obuf[4][64];

    const int tid  = threadIdx.x;
    const int lane = tid & 63;
    const int wave = tid >> 6;
    const int row0 = blockIdx.x * RPB;
    const int wrow0 = __builtin_amdgcn_readfirstlane(row0 + wave * 16);
    const int g   = lane >> 4;
    const int sub = lane & 15;
    const unsigned subOff = (unsigned)sub * 16u;

    {
        const int4* xb = (const int4*)(x + (size_t)wrow0 * 32);
        int4 a = xb[lane * 2];
        int4 b = xb[lane * 2 + 1];
        if ((lane & 3) == 3) { b.y = 7424; b.z = 7424; b.w = 7424; }
        ((int4*)&xlds[wave][0])[lane * 2]     = a;
        ((int4*)&xlds[wave][0])[lane * 2 + 1] = b;
    }

    #pragma unroll 4
    for (int r = 0; r < 16; ++r) {
        const int* xrow = &xlds[wave][r * 32 + g];
        uint4 v[8];
        #pragma unroll
        for (int b = 0; b < 8; ++b) {
            const int idx = xrow[4 * b];
            const unsigned off = ((unsigned)idx << 8) + subOff;
            v[b] = *(const uint4*)((const char*)emb16 + off);
        }
        h2v_t hacc[4];
        #pragma unroll
        for (int q = 0; q < 4; ++q) hacc[q] = (h2v_t)0;
        #pragma unroll
        for (int b = 0; b < 8; ++b) {
            hacc[0] += __builtin_bit_cast(h2v_t, v[b].x);
            hacc[1] += __builtin_bit_cast(h2v_t, v[b].y);
            hacc[2] += __builtin_bit_cast(h2v_t, v[b].z);
            hacc[3] += __builtin_bit_cast(h2v_t, v[b].w);
        }
        #pragma unroll
        for (int q = 0; q < 4; ++q) {
            unsigned u = __builtin_bit_cast(unsigned, hacc[q]);
            h2v_t t = __builtin_bit_cast(h2v_t, u);
            t += __builtin_bit_cast(h2v_t, (unsigned)__shfl_xor((int)u, 16));
            unsigned u2 = __builtin_bit_cast(unsigned, t);
            t += __builtin_bit_cast(h2v_t, (unsigned)__shfl_xor((int)u2, 32));
            hacc[q] = __builtin_elementwise_max(t, (h2v_t)0);
        }
        if (g == 0) {
            const int row = wave * 16 + r;
            #pragma unroll
            for (int q = 0; q < 4; ++q)
                hbuf[row][sub * 4 + q] = __builtin_bit_cast(__half2, hacc[q]);
        }
    }
    __syncthreads();

    {
        const int j0 = wave * 8;
        const int rr = lane;
        float acc[8];
        #pragma unroll
        for (int j = 0; j < 8; ++j) acc[j] = b2[j0 + j];
        #pragma unroll
        for (int d2 = 0; d2 < 64; ++d2) {
            const __half2 hv = hbuf[rr][d2];
            const float vx = __low2float(hv), vy = __high2float(hv);
            #pragma unroll
            for (int j = 0; j < 8; ++j) {
                const float* w = W2 + (size_t)(j0 + j) * 128 + d2 * 2;
                acc[j] = fmaf(vx, w[0], acc[j]);
                acc[j] = fmaf(vy, w[1], acc[j]);
            }
        }
        #pragma unroll
        for (int j = 0; j < 8; ++j) h2T[(j0 + j) * 64 + rr] = acc[j];
    }
    __syncthreads();

    {
        const int j0 = wave * 8;
        const int rr = lane;
        float h2v[32];
        #pragma unroll
        for (int k = 0; k < 32; ++k) h2v[k] = h2T[k * 64 + rr];
        float acc[8];
        #pragma unroll
        for (int j = 0; j < 8; ++j) acc[j] = b3[j0 + j];
        #pragma unroll
        for (int k = 0; k < 32; ++k) {
            const float pz = fmaxf(h2v[k], 0.f);
            const float mz = fmaxf(-h2v[k], 0.f);
            #pragma unroll
            for (int j = 0; j < 8; ++j) {
                const float* w = W3 + (size_t)(j0 + j) * 64;
                acc[j] = fmaf(pz, w[k],      acc[j]);
                acc[j] = fmaf(mz, w[32 + k], acc[j]);
            }
        }
        float o = 0.f;
        #pragma unroll
        for (int j = 0; j < 8; ++j) {
            const int jj = j0 + j;
            o = fmaf(fmaxf(acc[j], 0.f),  W4[jj],      o);
            o = fmaf(fmaxf(-acc[j], 0.f), W4[32 + jj], o);
        }
        obuf[wave][rr] = o;
    }
    __syncthreads();

    if (tid < 64) {
        const int row = row0 + tid;
        if (row < n)
            out[row] = obuf[0][tid] + obuf[1][tid] + obuf[2][tid] + obuf[3][tid];
    }
}

extern "C" void kernel_launch(void* const* d_in, const int* in_sizes, int n_in,
                              void* d_out, int out_size, void* d_ws, size_t ws_size,
                              hipStream_t stream) {
    const int*   x   = (const int*)  d_in[0];
    const float* emb = (const float*)d_in[1];
    const float* W2  = (const float*)d_in[2];
    const float* b2  = (const float*)d_in[3];
    const float* W3  = (const float*)d_in[4];
    const float* b3  = (const float*)d_in[5];
    const float* W4  = (const float*)d_in[6];
    float* out = (float*)d_out;
    const int n = out_size;                 // 131072 rows

    // workspace layout (16B-aligned sections)
    const size_t emb8_bytes = (size_t)7425 * 128;           // 950,400
    const size_t w2h_off    = emb8_bytes;                   // +8192
    const size_t w3h_off    = w2h_off + 8192;               // +4096
    const size_t slots_off  = w3h_off + 4096;               // +2048 (512 f32)
    const size_t amax_off   = slots_off + 2048;             // +16
    const size_t need       = amax_off + 16;

    if (ws_size >= need) {
        unsigned*     emb8  = (unsigned*)d_ws;
        _Float16*     W2h   = (_Float16*)((char*)d_ws + w2h_off);
        _Float16*     W3h   = (_Float16*)((char*)d_ws + w3h_off);
        float*        slots = (float*)((char*)d_ws + slots_off);
        float*        amaxp = (float*)((char*)d_ws + amax_off);
        const float4* emb4  = (const float4*)emb;

        const int n4 = 7424 * 32;   // 237,568 float4s
        hipLaunchKernelGGL(absmax_partial, dim3(NSLOTS), dim3(256), 0, stream,
                           emb4, slots, n4);

        const int nq = 7425 * 32;   // 237,600 u32s -> 929 blocks
        hipLaunchKernelGGL(prep_q8, dim3((nq + 255) / 256), dim3(256),
                           0, stream, emb4, emb8, W2, W3, W2h, W3h,
                           slots, amaxp);

        hipLaunchKernelGGL(nnue_q8, dim3((n + RPB - 1) / RPB), dim3(256),
                           0, stream, x, emb8, W2h, W3h, b2, b3, W4,
                           amaxp, out, n);
    } else {
        // legacy fallback: fp16 table + fp32-weight fused kernel
        __half2* emb16 = (__half2*)d_ws;
        const int npairs_real = 7424 * 64;
        const int npairs_tot  = 7425 * 64;
        hipLaunchKernelGGL(prep_fp16, dim3((npairs_tot + 255) / 256), dim3(256),
                           0, stream, emb, emb16, npairs_real, npairs_tot);
        hipLaunchKernelGGL(nnue_fused, dim3((n + RPB - 1) / RPB), dim3(256),
                           0, stream, x, (const __half*)emb16, W2, b2, W3, b3,
                           W4, out, n);
    }
}

// Round 9
// 107.904 us; speedup vs baseline: 3.8049x; 1.1130x over previous
//
#include <hip/hip_runtime.h>
#include <hip/hip_fp16.h>

// SilkNNUE R19b — resubmission of R19 (prior run died to container infra,
//   kernel never measured; gather re-audited: wIdx bijection, reduce-scatter
//   algebra, swizzle inversion, feature coverage all verified by hand).
//   Theory: divergent lane-address processing ~2 addr/cyc/CU is the wall.
//   R12/R16/R18 issue 512 lane-addr/row-iter -> 54.6us model ~= 52 meas.
//   R19 = 256 lane-addr (4 x uint4 loads/row, the int8 floor) AND ~12
//   DS-ops/row (3-level reduce-scatter, 7 shfl):
//     lane (g=lane>>4, sub=lane&15): s7=sub&7 picks the 16B chunk of the
//     128B int8 row; feature f = 8b+g+4*(sub>=8); idx via divergent
//     ds_read_u16. 8 masked 16-bit-slot accs (exact, max 8160), reduce-
//     scatter over lane bits 5,4,3 -> every lane owns fp16-word
//     wIdx = 8*s7+2g+sHi; full-lane cvt_pair; one swizzled ds_write_b32.
//   hT layout / dense MFMA / chain (absmax_partial -> prep_q8 -> nnue_q8):
//   R16/R18-verified, unchanged.

typedef _Float16 h2v_t  __attribute__((ext_vector_type(2)));
typedef _Float16 half8  __attribute__((ext_vector_type(8)));
typedef float    f32x4  __attribute__((ext_vector_type(4)));

constexpr int RPB    = 64;    // rows per block (main kernel)
constexpr int NSLOTS = 512;   // absmax partial slots

// ---- pass 1: per-block absmax partials (no init, no atomics) --------------
__global__ __launch_bounds__(256) void absmax_partial(
    const float4* __restrict__ emb4, float* __restrict__ slots, int n4)
{
    __shared__ float red[4];
    float m = 0.f;
    const int stride = NSLOTS * 256;
    for (int i = blockIdx.x * 256 + threadIdx.x; i < n4; i += stride) {
        float4 v = emb4[i];
        m = fmaxf(m, fmaxf(fmaxf(fabsf(v.x), fabsf(v.y)),
                           fmaxf(fabsf(v.z), fabsf(v.w))));
    }
    #pragma unroll
    for (int s = 1; s < 64; s <<= 1)
        m = fmaxf(m, __shfl_xor(m, s));
    if ((threadIdx.x & 63) == 0) red[threadIdx.x >> 6] = m;
    __syncthreads();
    if (threadIdx.x == 0)
        slots[blockIdx.x] = fmaxf(fmaxf(red[0], red[1]), fmaxf(red[2], red[3]));
}

// ---- pass 2: reduce slots + quantize emb -> u8 + W2/W3 -> fp16 ------------
__global__ __launch_bounds__(256) void prep_q8(
    const float4* __restrict__ emb4, unsigned* __restrict__ emb8,
    const float* __restrict__ W2, const float* __restrict__ W3,
    _Float16* __restrict__ W2h, _Float16* __restrict__ W3h,
    const float* __restrict__ slots, float* __restrict__ amax_out)
{
    __shared__ float red[4];
    const int tid = threadIdx.x;
    // block-local reduce of the 512 partials (2KB, L2-hot)
    float m = fmaxf(slots[tid], slots[tid + 256]);
    #pragma unroll
    for (int s = 1; s < 64; s <<= 1)
        m = fmaxf(m, __shfl_xor(m, s));
    if ((tid & 63) == 0) red[tid >> 6] = m;
    __syncthreads();
    const float amax = fmaxf(fmaxf(fmaxf(red[0], red[1]),
                                   fmaxf(red[2], red[3])), 1e-20f);
    const float qs = 127.f / amax;

    const int i = blockIdx.x * 256 + tid;
    if (i == 0) *amax_out = amax;
    if (i < 7425 * 32) {
        unsigned w = 0x80808080u;              // zero row 7424: q=0
        if (i < 7424 * 32) {
            float4 v = emb4[i];
            int q0 = min(127, max(-127, (int)rintf(v.x * qs)));
            int q1 = min(127, max(-127, (int)rintf(v.y * qs)));
            int q2 = min(127, max(-127, (int)rintf(v.z * qs)));
            int q3 = min(127, max(-127, (int)rintf(v.w * qs)));
            // byte order (d0,d2,d1,d3): lo-mask slots = dims (4j,4j+1),
            // hi-perm slots = dims (4j+2,4j+3)
            w = (unsigned)(q0 + 128)
              | ((unsigned)(q2 + 128) << 8)
              | ((unsigned)(q1 + 128) << 16)
              | ((unsigned)(q3 + 128) << 24);
        }
        emb8[i] = w;
    }
    if (i < 4096) W2h[i] = (_Float16)W2[i];
    if (i < 2048) W3h[i] = (_Float16)W3[i];
}

__device__ inline unsigned cvt_pair(unsigned w, float sc, float cb) {
    float f0 = (float)(w & 0xffffu) * sc + cb;
    float f1 = (float)(w >> 16)     * sc + cb;
    h2v_t h;
    h[0] = (_Float16)fmaxf(f0, 0.f);
    h[1] = (_Float16)fmaxf(f1, 0.f);
    return __builtin_bit_cast(unsigned, h);
}

// ---------------- fused kernel (int8, 4 scatter-loads/row) -----------------
__global__ __launch_bounds__(256, 8) void nnue_q8(
    const int*      __restrict__ x,      // (N,32)
    const unsigned* __restrict__ emb8,   // (7425,128) u8 permuted
    const _Float16* __restrict__ W2h,    // (32,128) fp16
    const _Float16* __restrict__ W3h,    // (32,64) fp16
    const float*    __restrict__ b2,
    const float*    __restrict__ b3,
    const float*    __restrict__ W4,     // (64,)
    const float*    __restrict__ amaxp,
    float*          __restrict__ out, int n)
{
    // per-wave: hT = 16 rows x 16 uint4 (swizzled), later aliased by a2 tile
    __shared__ __align__(16) char hmem[4][4096];   // 16384 B
    // per-wave packed u16 indices
    __shared__ __align__(16) char xmem[4][1024];   //  4096 B  (total 20480)

    const int tid  = threadIdx.x;
    const int lane = tid & 63;
    const int wave = tid >> 6;
    const int row0 = blockIdx.x * RPB;
    const int wrow0 = __builtin_amdgcn_readfirstlane(row0 + wave * 16);

    const float amax = *amaxp;
    const float sc = amax * (1.f / 127.f);
    const float cb = -4096.f * sc;      // bias removal: 32 features x 128

    const int g    = lane >> 4;         // 0..3
    const int sub  = lane & 15;         // 0..15
    const int s7   = sub & 7;           // 16B chunk of the 128B int8 row
    const bool sHi = (sub >= 8);
    const unsigned chunkOff = (unsigned)s7 * 16u;
    const char* embb = (const char*)emb8;

    unsigned short* xw = (unsigned short*)&xmem[wave][0];

    // ---- stage indices packed u16 (features 29..31 -> zero row 7424) ------
    {
        const int4* xb = (const int4*)(x + (size_t)wrow0 * 32);
        int4 a = xb[lane * 2];
        int4 b = xb[lane * 2 + 1];
        if ((lane & 3) == 3) { b.y = 7424; b.z = 7424; b.w = 7424; }
        uint4 pk;
        pk.x = ((unsigned)a.x & 0xffffu) | ((unsigned)a.y << 16);
        pk.y = ((unsigned)a.z & 0xffffu) | ((unsigned)a.w << 16);
        pk.z = ((unsigned)b.x & 0xffffu) | ((unsigned)b.y << 16);
        pk.w = ((unsigned)b.z & 0xffffu) | ((unsigned)b.w << 16);
        ((uint4*)xw)[lane] = pk;
    }
    // same-wave DS ordering; no barriers anywhere in this kernel.

    const bool gHi  = (g >= 2);
    const bool gOdd = (g & 1);
    // lane finally owns fp16-word wIdx = 8*s7 + 2*g + sHi of each row
    const int wIdx = 8 * s7 + 2 * g + (sHi ? 1 : 0);
    const int granule = wIdx >> 2;          // 16B granule 0..15
    const int wInG    = (wIdx & 3) * 4;     // byte within granule

    // ---- gather: 4 x uint4 per row (256 lane-addr), reduce-scatter --------
    #pragma unroll 4
    for (int r = 0; r < 16; ++r) {
        // feature for load b: sub<8 -> 8b+g ; sub>=8 -> 8b+4+g
        const int fbase = r * 32 + g + (sHi ? 4 : 0);
        uint4 v[4];
        #pragma unroll
        for (int b = 0; b < 4; ++b) {
            const unsigned idx = xw[fbase + 8 * b];   // divergent ds_read_u16
            v[b] = *(const uint4*)(embb + ((idx << 7) + chunkOff));
        }
        // accumulate 4 features into 8 accs (16-bit slots, exact)
        unsigned a0 = 0, a1 = 0, a2 = 0, a3 = 0, a4 = 0, a5 = 0, a6 = 0, a7 = 0;
        #pragma unroll
        for (int b = 0; b < 4; ++b) {
            a0 += v[b].x & 0x00ff00ffu;
            a1 += __builtin_amdgcn_perm(0u, v[b].x, 0x0c030c01u);
            a2 += v[b].y & 0x00ff00ffu;
            a3 += __builtin_amdgcn_perm(0u, v[b].y, 0x0c030c01u);
            a4 += v[b].z & 0x00ff00ffu;
            a5 += __builtin_amdgcn_perm(0u, v[b].z, 0x0c030c01u);
            a6 += v[b].w & 0x00ff00ffu;
            a7 += __builtin_amdgcn_perm(0u, v[b].w, 0x0c030c01u);
        }
        // L1 (xor 32, g-bit1): keep words {0,1} if g<2 else {2,3}
        unsigned b0, b1, b2, b3;
        {
            const unsigned s0 = gHi ? a0 : a4;
            const unsigned s1 = gHi ? a1 : a5;
            const unsigned s2 = gHi ? a2 : a6;
            const unsigned s3 = gHi ? a3 : a7;
            b0 = (gHi ? a4 : a0) + (unsigned)__shfl_xor((int)s0, 32);
            b1 = (gHi ? a5 : a1) + (unsigned)__shfl_xor((int)s1, 32);
            b2 = (gHi ? a6 : a2) + (unsigned)__shfl_xor((int)s2, 32);
            b3 = (gHi ? a7 : a3) + (unsigned)__shfl_xor((int)s3, 32);
        }
        // L2 (xor 16, g-bit0): keep one word (lo/hi acc pair)
        unsigned c0, c1;
        {
            const unsigned s0 = gOdd ? b0 : b2;
            const unsigned s1 = gOdd ? b1 : b3;
            c0 = (gOdd ? b2 : b0) + (unsigned)__shfl_xor((int)s0, 16);
            c1 = (gOdd ? b3 : b1) + (unsigned)__shfl_xor((int)s1, 16);
        }
        // L3 (xor 8, sub-bit3): keep lo (sub<8) or hi (sub>=8) dim-pair
        const unsigned sz = sHi ? c0 : c1;
        const unsigned Z  = (sHi ? c1 : c0) + (unsigned)__shfl_xor((int)sz, 8);
        // full-wave store: fp16-word wIdx of row r, swizzled granule
        const int byteOff = r * 256 + (((granule ^ (r & 7)) << 4) | wInG);
        *(unsigned*)(&hmem[wave][byteOff]) = cvt_pair(Z, sc, cb);
    }

    // ================= dense (per-wave MFMA, same wave's 16 rows) ==========
    const uint4* hT = (const uint4*)&hmem[wave][0];
    const int q  = lane >> 4;     // k-quad
    const int nn = lane & 15;     // A row m / B col n / C col n

    half8 bw2[2][4];
    #pragma unroll
    for (int nt = 0; nt < 2; ++nt)
        #pragma unroll
        for (int kk = 0; kk < 4; ++kk)
            bw2[nt][kk] = __builtin_bit_cast(half8,
                *(const uint4*)((const char*)W2h +
                    ((nt * 16 + nn) * 128 + kk * 32 + q * 8) * 2));

    half8 af[4];
    #pragma unroll
    for (int kk = 0; kk < 4; ++kk)
        af[kk] = __builtin_bit_cast(half8,
            hT[nn * 16 + ((4 * kk + q) ^ (nn & 7))]);

    f32x4 acc0 = {0.f, 0.f, 0.f, 0.f}, acc1 = {0.f, 0.f, 0.f, 0.f};
    #pragma unroll
    for (int kk = 0; kk < 4; ++kk) {
        acc0 = __builtin_amdgcn_mfma_f32_16x16x32_f16(af[kk], bw2[0][kk], acc0, 0, 0, 0);
        acc1 = __builtin_amdgcn_mfma_f32_16x16x32_f16(af[kk], bw2[1][kk], acc1, 0, 0, 0);
    }
    const float bb0 = b2[nn], bb1 = b2[16 + nn];

    // CReLU + transpose via LDS (stride 68 halfs). a2 aliases hT:
    // all hT (af) reads completed above, same-wave program order.
    _Float16* a2p = (_Float16*)&hmem[wave][0];
    #pragma unroll
    for (int r = 0; r < 4; ++r) {
        const float v0 = acc0[r] + bb0;
        const float v1 = acc1[r] + bb1;
        const int m = q * 4 + r;
        a2p[m * 68 + nn]      = (_Float16)fmaxf(v0, 0.f);
        a2p[m * 68 + 16 + nn] = (_Float16)fmaxf(v1, 0.f);
        a2p[m * 68 + 32 + nn] = (_Float16)fmaxf(-v0, 0.f);
        a2p[m * 68 + 48 + nn] = (_Float16)fmaxf(-v1, 0.f);
    }

    half8 bw3[2][2];
    #pragma unroll
    for (int nt = 0; nt < 2; ++nt)
        #pragma unroll
        for (int kk = 0; kk < 2; ++kk)
            bw3[nt][kk] = __builtin_bit_cast(half8,
                *(const uint4*)((const char*)W3h +
                    ((nt * 16 + nn) * 64 + kk * 32 + q * 8) * 2));

    half8 a2f[2];
    #pragma unroll
    for (int kk = 0; kk < 2; ++kk) {
        const _Float16* pp = &a2p[nn * 68 + kk * 32 + q * 8];
        half8 t;
        #pragma unroll
        for (int j = 0; j < 8; ++j) t[j] = pp[j];
        a2f[kk] = t;
    }

    f32x4 acc30 = {0.f, 0.f, 0.f, 0.f}, acc31 = {0.f, 0.f, 0.f, 0.f};
    #pragma unroll
    for (int kk = 0; kk < 2; ++kk) {
        acc30 = __builtin_amdgcn_mfma_f32_16x16x32_f16(a2f[kk], bw3[0][kk], acc30, 0, 0, 0);
        acc31 = __builtin_amdgcn_mfma_f32_16x16x32_f16(a2f[kk], bw3[1][kk], acc31, 0, 0, 0);
    }
    const float bb30 = b3[nn], bb31 = b3[16 + nn];

    const float w4a = W4[nn],      w4b = W4[16 + nn];
    const float w4c = W4[32 + nn], w4d = W4[48 + nn];
    float o[4];
    #pragma unroll
    for (int r = 0; r < 4; ++r) {
        const float v0 = acc30[r] + bb30;
        const float v1 = acc31[r] + bb31;
        o[r] = fmaxf(v0, 0.f) * w4a + fmaxf(-v0, 0.f) * w4c
             + fmaxf(v1, 0.f) * w4b + fmaxf(-v1, 0.f) * w4d;
    }
    #pragma unroll
    for (int s = 1; s < 16; s <<= 1) {
        #pragma unroll
        for (int r = 0; r < 4; ++r) o[r] += __shfl_xor(o[r], s);
    }
    if (nn == 0) {
        #pragma unroll
        for (int r = 0; r < 4; ++r) {
            const int row = wrow0 + q * 4 + r;
            if (row < n) out[row] = o[r];
        }
    }
}

// ---------------- fallback (fp16 table + fp32-weight fused) ----------------
__global__ __launch_bounds__(256) void prep_fp16(
    const float* __restrict__ emb, __half2* __restrict__ emb16,
    int npairs_real, int npairs_tot)
{
    int i = blockIdx.x * blockDim.x + threadIdx.x;
    if (i < npairs_tot) {
        float2 v = make_float2(0.f, 0.f);
        if (i < npairs_real) v = ((const float2*)emb)[i];
        emb16[i] = __floats2half2_rn(v.x, v.y);
    }
}

__global__ __launch_bounds__(256) void nnue_fused(
    const int*    __restrict__ x,
    const __half* __restrict__ emb16,
    const float*  __restrict__ W2, const float* __restrict__ b2,
    const float*  __restrict__ W3, const float* __restrict__ b3,
    const float*  __restrict__ W4,
    float*        __restrict__ out, int n)
{
    __shared__ int     xlds[4][512];
    __shared__ __half2 hbuf[64][65];
    __shared__ float   h2T[32 * 64];
    __shared__ float   obuf[4][64];

    const int tid  = threadIdx.x;
    const int lane = tid & 63;
    const int wave = tid >> 6;
    const int row0 = blockIdx.x * RPB;
    const int wrow0 = __builtin_amdgcn_readfirstlane(row0 + wave * 16);
    const int g   = lane >> 4;
    const int sub = lane & 15;
    const unsigned subOff = (unsigned)sub * 16u;

    {
        const int4* xb = (const int4*)(x + (size_t)wrow0 * 32);
        int4 a = xb[lane * 2];
        int4 b = xb[lane * 2 + 1];
        if ((lane & 3) == 3) { b.y = 7424; b.z = 7424; b.w = 7424; }
        ((int4*)&xlds[wave][0])[lane * 2]     = a;
        ((int4*)&xlds[wave][0])[lane * 2 + 1] = b;
    }

    #pragma unroll 4
    for (int r = 0; r < 16; ++r) {
        const int* xrow = &xlds[wave][r * 32 + g];
        uint4 v[8];
        #pragma unroll
        for (int b = 0; b < 8; ++b) {
            const int idx = xrow[4 * b];
            const unsigned off = ((unsigned)idx << 8) + subOff;
            v[b] = *(const uint4*)((const char*)emb16 + off);
        }
        h2v_t hacc[4];
        #pragma unroll
        for (int q = 0; q < 4; ++q) hacc[q] = (h2v_t)0;
        #pragma unroll
        for (int b = 0; b < 8; ++b) {
            hacc[0] += __builtin_bit_cast(h2v_t, v[b].x);
            hacc[1] += __builtin_bit_cast(h2v_t, v[b].y);
            hacc[2] += __builtin_bit_cast(h2v_t, v[b].z);
            hacc[3] += __builtin_bit_cast(h2v_t, v[b].w);
        }
        #pragma unroll
        for (int q = 0; q < 4; ++q) {
            unsigned u = __builtin_bit_cast(unsigned, hacc[q]);
            h2v_t t = __builtin_bit_cast(h2v_t, u);
            t += __builtin_bit_cast(h2v_t, (unsigned)__shfl_xor((int)u, 16));
            unsigned u2 = __builtin_bit_cast(unsigned, t);
            t += __builtin_bit_cast(h2v_t, (unsigned)__shfl_xor((int)u2, 32));
            hacc[q] = __builtin_elementwise_max(t, (h2v_t)0);
        }
        if (g == 0) {
            const int row = wave * 16 + r;
            #pragma unroll
            for (int q = 0; q < 4; ++q)
                hbuf[row][sub * 4 + q] = __builtin_bit_cast(__half2, hacc[q]);
        }
    }
    __syncthreads();

    {
        const int j0 = wave * 8;
        const int rr = lane;
        float acc[8];
        #pragma unroll
        for (int j = 0; j < 8; ++j) acc[j] = b2[j0 + j];
        #pragma unroll
        for (int d2 = 0; d2 < 64; ++d2) {
            const __half2 hv = hbuf[rr][d2];
            const float vx = __low2float(hv), vy = __high2float(hv);
            #pragma unroll
            for (int j = 0; j < 8; ++j) {
                const float* w = W2 + (size_t)(j0 + j) * 128 + d2 * 2;
                acc[j] = fmaf(vx, w[0], acc[j]);
                acc[j] = fmaf(vy, w[1], acc[j]);
            }
        }
        #pragma unroll
        for (int j = 0; j < 8; ++j) h2T[(j0 + j) * 64 + rr] = acc[j];
    }
    __syncthreads();

    {
        const int j0 = wave * 8;
        const int rr = lane;
        float h2v[32];
        #pragma unroll
        for (int k = 0; k < 32; ++k) h2v[k] = h2T[k * 64 + rr];
        float acc[8];
        #pragma unroll
        for (int j = 0; j < 8; ++j) acc[j] = b3[j0 + j];
        #pragma unroll
        for (int k = 0; k < 32; ++k) {
            const float pz = fmaxf(h2v[k], 0.f);
            const float mz = fmaxf(-h2v[k], 0.f);
            #pragma unroll
            for (int j = 0; j < 8; ++j) {
                const float* w = W3 + (size_t)(j0 + j) * 64;
                acc[j] = fmaf(pz, w[k],      acc[j]);
                acc[j] = fmaf(mz, w[32 + k], acc[j]);
            }
        }
        float o = 0.f;
        #pragma unroll
        for (int j = 0; j < 8; ++j) {
            const int jj = j0 + j;
            o = fmaf(fmaxf(acc[j], 0.f),  W4[jj],      o);
            o = fmaf(fmaxf(-acc[j], 0.f), W4[32 + jj], o);
        }
        obuf[wave][rr] = o;
    }
    __syncthreads();

    if (tid < 64) {
        const int row = row0 + tid;
        if (row < n)
            out[row] = obuf[0][tid] + obuf[1][tid] + obuf[2][tid] + obuf[3][tid];
    }
}

extern "C" void kernel_launch(void* const* d_in, const int* in_sizes, int n_in,
                              void* d_out, int out_size, void* d_ws, size_t ws_size,
                              hipStream_t stream) {
    const int*   x   = (const int*)  d_in[0];
    const float* emb = (const float*)d_in[1];
    const float* W2  = (const float*)d_in[2];
    const float* b2  = (const float*)d_in[3];
    const float* W3  = (const float*)d_in[4];
    const float* b3  = (const float*)d_in[5];
    const float* W4  = (const float*)d_in[6];
    float* out = (float*)d_out;
    const int n = out_size;                 // 131072 rows

    // workspace layout (16B-aligned sections)
    const size_t emb8_bytes = (size_t)7425 * 128;           // 950,400
    const size_t w2h_off    = emb8_bytes;                   // +8192
    const size_t w3h_off    = w2h_off + 8192;               // +4096
    const size_t slots_off  = w3h_off + 4096;               // +2048 (512 f32)
    const size_t amax_off   = slots_off + 2048;             // +16
    const size_t need       = amax_off + 16;

    if (ws_size >= need) {
        unsigned*     emb8  = (unsigned*)d_ws;
        _Float16*     W2h   = (_Float16*)((char*)d_ws + w2h_off);
        _Float16*     W3h   = (_Float16*)((char*)d_ws + w3h_off);
        float*        slots = (float*)((char*)d_ws + slots_off);
        float*        amaxp = (float*)((char*)d_ws + amax_off);
        const float4* emb4  = (const float4*)emb;

        const int n4 = 7424 * 32;   // 237,568 float4s
        hipLaunchKernelGGL(absmax_partial, dim3(NSLOTS), dim3(256), 0, stream,
                           emb4, slots, n4);

        const int nq = 7425 * 32;   // 237,600 u32s -> 929 blocks
        hipLaunchKernelGGL(prep_q8, dim3((nq + 255) / 256), dim3(256),
                           0, stream, emb4, emb8, W2, W3, W2h, W3h,
                           slots, amaxp);

        hipLaunchKernelGGL(nnue_q8, dim3((n + RPB - 1) / RPB), dim3(256),
                           0, stream, x, emb8, W2h, W3h, b2, b3, W4,
                           amaxp, out, n);
    } else {
        // legacy fallback: fp16 table + fp32-weight fused kernel
        __half2* emb16 = (__half2*)d_ws;
        const int npairs_real = 7424 * 64;
        const int npairs_tot  = 7425 * 64;
        hipLaunchKernelGGL(prep_fp16, dim3((npairs_tot + 255) / 256), dim3(256),
                           0, stream, emb, emb16, npairs_real, npairs_tot);
        hipLaunchKernelGGL(nnue_fused, dim3((n + RPB - 1) / RPB), dim3(256),
                           0, stream, x, (const __half*)emb16, W2, b2, W3, b3,
                           W4, out, n);
    }
}

// Round 10
// 106.727 us; speedup vs baseline: 3.8469x; 1.0110x over previous
//
#include <hip/hip_runtime.h>
#include <hip/hip_fp16.h>

// SilkNNUE R20 — R19 gather + 1-row-ahead load pipeline (sched_barrier-pinned).
//   R19b confirmed the TA divergent-address model (~2 addr/cyc/CU):
//   halving lane-addresses (512->256/row) took nnue_q8 52 -> ~39us.
//   Residual ~12us = exposed idx->addr->load latency tails + ramp.
//   R20: issue row r+1's 4 idx ds_reads + 4 uint4 loads BEFORE combining
//   row r, pinned with __builtin_amdgcn_sched_barrier(0) (R17's pipeline
//   collapsed because hipcc re-serialized under the VGPR-64 cap; now
//   __launch_bounds__(256,6) -> cap ~84, 2 rows in flight ~60 VGPR, and
//   the barrier stops the scheduler sinking the loads).
//   6 blocks/CU (24 waves) vs 8: perf-neutral in this regime (R11 vs R12).
//   W2h/W3h conversion moved into absmax_partial (amax-independent).
//   Chain: absmax_partial(+W) -> prep_q8 -> nnue_q8. Dense MFMA unchanged.

typedef _Float16 h2v_t  __attribute__((ext_vector_type(2)));
typedef _Float16 half8  __attribute__((ext_vector_type(8)));
typedef float    f32x4  __attribute__((ext_vector_type(4)));

constexpr int RPB    = 64;    // rows per block (main kernel)
constexpr int NSLOTS = 512;   // absmax partial slots

// ---- pass 1: per-block absmax partials + W2/W3 -> fp16 --------------------
__global__ __launch_bounds__(256) void absmax_partial(
    const float4* __restrict__ emb4, float* __restrict__ slots,
    const float* __restrict__ W2, const float* __restrict__ W3,
    _Float16* __restrict__ W2h, _Float16* __restrict__ W3h, int n4)
{
    __shared__ float red[4];
    const int tid = threadIdx.x;
    const int i0  = blockIdx.x * 256 + tid;
    float m = 0.f;
    const int stride = NSLOTS * 256;
    for (int i = i0; i < n4; i += stride) {
        float4 v = emb4[i];
        m = fmaxf(m, fmaxf(fmaxf(fabsf(v.x), fabsf(v.y)),
                           fmaxf(fabsf(v.z), fabsf(v.w))));
    }
    #pragma unroll
    for (int s = 1; s < 64; s <<= 1)
        m = fmaxf(m, __shfl_xor(m, s));
    if ((tid & 63) == 0) red[tid >> 6] = m;
    // W conversion is amax-independent; fill idle slots of early blocks
    if (i0 < 4096) W2h[i0] = (_Float16)W2[i0];
    if (i0 < 2048) W3h[i0] = (_Float16)W3[i0];
    __syncthreads();
    if (tid == 0)
        slots[blockIdx.x] = fmaxf(fmaxf(red[0], red[1]), fmaxf(red[2], red[3]));
}

// ---- pass 2: reduce slots + quantize emb -> u8 ----------------------------
__global__ __launch_bounds__(256) void prep_q8(
    const float4* __restrict__ emb4, unsigned* __restrict__ emb8,
    const float* __restrict__ slots, float* __restrict__ amax_out)
{
    __shared__ float red[4];
    const int tid = threadIdx.x;
    // block-local reduce of the 512 partials (2KB, L2-hot)
    float m = fmaxf(slots[tid], slots[tid + 256]);
    #pragma unroll
    for (int s = 1; s < 64; s <<= 1)
        m = fmaxf(m, __shfl_xor(m, s));
    if ((tid & 63) == 0) red[tid >> 6] = m;
    __syncthreads();
    const float amax = fmaxf(fmaxf(fmaxf(red[0], red[1]),
                                   fmaxf(red[2], red[3])), 1e-20f);
    const float qs = 127.f / amax;

    const int i = blockIdx.x * 256 + tid;
    if (i == 0) *amax_out = amax;
    if (i < 7425 * 32) {
        unsigned w = 0x80808080u;              // zero row 7424: q=0
        if (i < 7424 * 32) {
            float4 v = emb4[i];
            int q0 = min(127, max(-127, (int)rintf(v.x * qs)));
            int q1 = min(127, max(-127, (int)rintf(v.y * qs)));
            int q2 = min(127, max(-127, (int)rintf(v.z * qs)));
            int q3 = min(127, max(-127, (int)rintf(v.w * qs)));
            // byte order (d0,d2,d1,d3): lo-mask slots = dims (4j,4j+1),
            // hi-perm slots = dims (4j+2,4j+3)
            w = (unsigned)(q0 + 128)
              | ((unsigned)(q2 + 128) << 8)
              | ((unsigned)(q1 + 128) << 16)
              | ((unsigned)(q3 + 128) << 24);
        }
        emb8[i] = w;
    }
}

__device__ inline unsigned cvt_pair(unsigned w, float sc, float cb) {
    float f0 = (float)(w & 0xffffu) * sc + cb;
    float f1 = (float)(w >> 16)     * sc + cb;
    h2v_t h;
    h[0] = (_Float16)fmaxf(f0, 0.f);
    h[1] = (_Float16)fmaxf(f1, 0.f);
    return __builtin_bit_cast(unsigned, h);
}

// ---------------- fused kernel (int8, pipelined 4-load gather) -------------
__global__ __launch_bounds__(256, 6) void nnue_q8(
    const int*      __restrict__ x,      // (N,32)
    const unsigned* __restrict__ emb8,   // (7425,128) u8 permuted
    const _Float16* __restrict__ W2h,    // (32,128) fp16
    const _Float16* __restrict__ W3h,    // (32,64) fp16
    const float*    __restrict__ b2,
    const float*    __restrict__ b3,
    const float*    __restrict__ W4,     // (64,)
    const float*    __restrict__ amaxp,
    float*          __restrict__ out, int n)
{
    // per-wave: hT = 16 rows x 16 uint4 (swizzled), later aliased by a2 tile
    __shared__ __align__(16) char hmem[4][4096];   // 16384 B
    // per-wave packed u16 indices
    __shared__ __align__(16) char xmem[4][1024];   //  4096 B  (total 20480)

    const int tid  = threadIdx.x;
    const int lane = tid & 63;
    const int wave = tid >> 6;
    const int row0 = blockIdx.x * RPB;
    const int wrow0 = __builtin_amdgcn_readfirstlane(row0 + wave * 16);

    const float amax = *amaxp;
    const float sc = amax * (1.f / 127.f);
    const float cb = -4096.f * sc;      // bias removal: 32 features x 128

    const int g    = lane >> 4;         // 0..3
    const int sub  = lane & 15;         // 0..15
    const int s7   = sub & 7;           // 16B chunk of the 128B int8 row
    const bool sHi = (sub >= 8);
    const unsigned chunkOff = (unsigned)s7 * 16u;
    const char* embb = (const char*)emb8;

    unsigned short* xw = (unsigned short*)&xmem[wave][0];

    // ---- stage indices packed u16 (features 29..31 -> zero row 7424) ------
    {
        const int4* xb = (const int4*)(x + (size_t)wrow0 * 32);
        int4 a = xb[lane * 2];
        int4 b = xb[lane * 2 + 1];
        if ((lane & 3) == 3) { b.y = 7424; b.z = 7424; b.w = 7424; }
        uint4 pk;
        pk.x = ((unsigned)a.x & 0xffffu) | ((unsigned)a.y << 16);
        pk.y = ((unsigned)a.z & 0xffffu) | ((unsigned)a.w << 16);
        pk.z = ((unsigned)b.x & 0xffffu) | ((unsigned)b.y << 16);
        pk.w = ((unsigned)b.z & 0xffffu) | ((unsigned)b.w << 16);
        ((uint4*)xw)[lane] = pk;
    }
    // same-wave DS ordering; no barriers anywhere in this kernel.

    const bool gHi  = (g >= 2);
    const bool gOdd = (g & 1);
    // lane finally owns fp16-word wIdx = 8*s7 + 2*g + sHi of each row
    const int wIdx = 8 * s7 + 2 * g + (sHi ? 1 : 0);
    const int granule = wIdx >> 2;          // 16B granule 0..15
    const int wInG    = (wIdx & 3) * 4;     // byte within granule
    const int fOff    = g + (sHi ? 4 : 0);  // feature offset within octet

    // ---- gather: 4 x uint4 per row, 1-row-ahead pipeline, reduce-scatter --
    uint4 c0, c1, c2, c3;
    {
        const unsigned short* xr = xw + fOff;
        c0 = *(const uint4*)(embb + (((unsigned)xr[0]  << 7) + chunkOff));
        c1 = *(const uint4*)(embb + (((unsigned)xr[8]  << 7) + chunkOff));
        c2 = *(const uint4*)(embb + (((unsigned)xr[16] << 7) + chunkOff));
        c3 = *(const uint4*)(embb + (((unsigned)xr[24] << 7) + chunkOff));
    }
    #pragma unroll
    for (int r = 0; r < 16; ++r) {
        uint4 n0, n1, n2, n3;
        if (r < 15) {
            const unsigned short* xr = xw + (r + 1) * 32 + fOff;
            n0 = *(const uint4*)(embb + (((unsigned)xr[0]  << 7) + chunkOff));
            n1 = *(const uint4*)(embb + (((unsigned)xr[8]  << 7) + chunkOff));
            n2 = *(const uint4*)(embb + (((unsigned)xr[16] << 7) + chunkOff));
            n3 = *(const uint4*)(embb + (((unsigned)xr[24] << 7) + chunkOff));
            // pin: next-row loads must be issued before this row's combine
            __builtin_amdgcn_sched_barrier(0);
        }
        // accumulate 4 features into 8 accs (16-bit slots, exact, max 8160)
        unsigned a0 = 0, a1 = 0, a2 = 0, a3 = 0, a4 = 0, a5 = 0, a6 = 0, a7 = 0;
        {
            a0 += c0.x & 0x00ff00ffu;
            a1 += __builtin_amdgcn_perm(0u, c0.x, 0x0c030c01u);
            a2 += c0.y & 0x00ff00ffu;
            a3 += __builtin_amdgcn_perm(0u, c0.y, 0x0c030c01u);
            a4 += c0.z & 0x00ff00ffu;
            a5 += __builtin_amdgcn_perm(0u, c0.z, 0x0c030c01u);
            a6 += c0.w & 0x00ff00ffu;
            a7 += __builtin_amdgcn_perm(0u, c0.w, 0x0c030c01u);

            a0 += c1.x & 0x00ff00ffu;
            a1 += __builtin_amdgcn_perm(0u, c1.x, 0x0c030c01u);
            a2 += c1.y & 0x00ff00ffu;
            a3 += __builtin_amdgcn_perm(0u, c1.y, 0x0c030c01u);
            a4 += c1.z & 0x00ff00ffu;
            a5 += __builtin_amdgcn_perm(0u, c1.z, 0x0c030c01u);
            a6 += c1.w & 0x00ff00ffu;
            a7 += __builtin_amdgcn_perm(0u, c1.w, 0x0c030c01u);

            a0 += c2.x & 0x00ff00ffu;
            a1 += __builtin_amdgcn_perm(0u, c2.x, 0x0c030c01u);
            a2 += c2.y & 0x00ff00ffu;
            a3 += __builtin_amdgcn_perm(0u, c2.y, 0x0c030c01u);
            a4 += c2.z & 0x00ff00ffu;
            a5 += __builtin_amdgcn_perm(0u, c2.z, 0x0c030c01u);
            a6 += c2.w & 0x00ff00ffu;
            a7 += __builtin_amdgcn_perm(0u, c2.w, 0x0c030c01u);

            a0 += c3.x & 0x00ff00ffu;
            a1 += __builtin_amdgcn_perm(0u, c3.x, 0x0c030c01u);
            a2 += c3.y & 0x00ff00ffu;
            a3 += __builtin_amdgcn_perm(0u, c3.y, 0x0c030c01u);
            a4 += c3.z & 0x00ff00ffu;
            a5 += __builtin_amdgcn_perm(0u, c3.z, 0x0c030c01u);
            a6 += c3.w & 0x00ff00ffu;
            a7 += __builtin_amdgcn_perm(0u, c3.w, 0x0c030c01u);
        }
        // L1 (xor 32, g-bit1): keep words {0,1} if g<2 else {2,3}
        unsigned b0, b1, b2, b3;
        {
            const unsigned s0 = gHi ? a0 : a4;
            const unsigned s1 = gHi ? a1 : a5;
            const unsigned s2 = gHi ? a2 : a6;
            const unsigned s3 = gHi ? a3 : a7;
            b0 = (gHi ? a4 : a0) + (unsigned)__shfl_xor((int)s0, 32);
            b1 = (gHi ? a5 : a1) + (unsigned)__shfl_xor((int)s1, 32);
            b2 = (gHi ? a6 : a2) + (unsigned)__shfl_xor((int)s2, 32);
            b3 = (gHi ? a7 : a3) + (unsigned)__shfl_xor((int)s3, 32);
        }
        // L2 (xor 16, g-bit0): keep one word (lo/hi acc pair)
        unsigned cc0, cc1;
        {
            const unsigned s0 = gOdd ? b0 : b2;
            const unsigned s1 = gOdd ? b1 : b3;
            cc0 = (gOdd ? b2 : b0) + (unsigned)__shfl_xor((int)s0, 16);
            cc1 = (gOdd ? b3 : b1) + (unsigned)__shfl_xor((int)s1, 16);
        }
        // L3 (xor 8, sub-bit3): keep lo (sub<8) or hi (sub>=8) dim-pair
        const unsigned sz = sHi ? cc0 : cc1;
        const unsigned Z  = (sHi ? cc1 : cc0) + (unsigned)__shfl_xor((int)sz, 8);
        // full-wave store: fp16-word wIdx of row r, swizzled granule
        const int byteOff = r * 256 + (((granule ^ (r & 7)) << 4) | wInG);
        *(unsigned*)(&hmem[wave][byteOff]) = cvt_pair(Z, sc, cb);

        if (r < 15) { c0 = n0; c1 = n1; c2 = n2; c3 = n3; }
    }

    // ================= dense (per-wave MFMA, same wave's 16 rows) ==========
    const uint4* hT = (const uint4*)&hmem[wave][0];
    const int q  = lane >> 4;     // k-quad
    const int nn = lane & 15;     // A row m / B col n / C col n

    half8 bw2[2][4];
    #pragma unroll
    for (int nt = 0; nt < 2; ++nt)
        #pragma unroll
        for (int kk = 0; kk < 4; ++kk)
            bw2[nt][kk] = __builtin_bit_cast(half8,
                *(const uint4*)((const char*)W2h +
                    ((nt * 16 + nn) * 128 + kk * 32 + q * 8) * 2));

    half8 af[4];
    #pragma unroll
    for (int kk = 0; kk < 4; ++kk)
        af[kk] = __builtin_bit_cast(half8,
            hT[nn * 16 + ((4 * kk + q) ^ (nn & 7))]);

    f32x4 acc0 = {0.f, 0.f, 0.f, 0.f}, acc1 = {0.f, 0.f, 0.f, 0.f};
    #pragma unroll
    for (int kk = 0; kk < 4; ++kk) {
        acc0 = __builtin_amdgcn_mfma_f32_16x16x32_f16(af[kk], bw2[0][kk], acc0, 0, 0, 0);
        acc1 = __builtin_amdgcn_mfma_f32_16x16x32_f16(af[kk], bw2[1][kk], acc1, 0, 0, 0);
    }
    const float bb0 = b2[nn], bb1 = b2[16 + nn];

    // CReLU + transpose via LDS (stride 68 halfs). a2 aliases hT:
    // all hT (af) reads completed above, same-wave program order.
    _Float16* a2p = (_Float16*)&hmem[wave][0];
    #pragma unroll
    for (int r = 0; r < 4; ++r) {
        const float v0 = acc0[r] + bb0;
        const float v1 = acc1[r] + bb1;
        const int m = q * 4 + r;
        a2p[m * 68 + nn]      = (_Float16)fmaxf(v0, 0.f);
        a2p[m * 68 + 16 + nn] = (_Float16)fmaxf(v1, 0.f);
        a2p[m * 68 + 32 + nn] = (_Float16)fmaxf(-v0, 0.f);
        a2p[m * 68 + 48 + nn] = (_Float16)fmaxf(-v1, 0.f);
    }

    half8 bw3[2][2];
    #pragma unroll
    for (int nt = 0; nt < 2; ++nt)
        #pragma unroll
        for (int kk = 0; kk < 2; ++kk)
            bw3[nt][kk] = __builtin_bit_cast(half8,
                *(const uint4*)((const char*)W3h +
                    ((nt * 16 + nn) * 64 + kk * 32 + q * 8) * 2));

    half8 a2f[2];
    #pragma unroll
    for (int kk = 0; kk < 2; ++kk) {
        const _Float16* pp = &a2p[nn * 68 + kk * 32 + q * 8];
        half8 t;
        #pragma unroll
        for (int j = 0; j < 8; ++j) t[j] = pp[j];
        a2f[kk] = t;
    }

    f32x4 acc30 = {0.f, 0.f, 0.f, 0.f}, acc31 = {0.f, 0.f, 0.f, 0.f};
    #pragma unroll
    for (int kk = 0; kk < 2; ++kk) {
        acc30 = __builtin_amdgcn_mfma_f32_16x16x32_f16(a2f[kk], bw3[0][kk], acc30, 0, 0, 0);
        acc31 = __builtin_amdgcn_mfma_f32_16x16x32_f16(a2f[kk], bw3[1][kk], acc31, 0, 0, 0);
    }
    const float bb30 = b3[nn], bb31 = b3[16 + nn];

    const float w4a = W4[nn],      w4b = W4[16 + nn];
    const float w4c = W4[32 + nn], w4d = W4[48 + nn];
    float o[4];
    #pragma unroll
    for (int r = 0; r < 4; ++r) {
        const float v0 = acc30[r] + bb30;
        const float v1 = acc31[r] + bb31;
        o[r] = fmaxf(v0, 0.f) * w4a + fmaxf(-v0, 0.f) * w4c
             + fmaxf(v1, 0.f) * w4b + fmaxf(-v1, 0.f) * w4d;
    }
    #pragma unroll
    for (int s = 1; s < 16; s <<= 1) {
        #pragma unroll
        for (int r = 0; r < 4; ++r) o[r] += __shfl_xor(o[r], s);
    }
    if (nn == 0) {
        #pragma unroll
        for (int r = 0; r < 4; ++r) {
            const int row = wrow0 + q * 4 + r;
            if (row < n) out[row] = o[r];
        }
    }
}

// ---------------- fallback (fp16 table + fp32-weight fused) ----------------
__global__ __launch_bounds__(256) void prep_fp16(
    const float* __restrict__ emb, __half2* __restrict__ emb16,
    int npairs_real, int npairs_tot)
{
    int i = blockIdx.x * blockDim.x + threadIdx.x;
    if (i < npairs_tot) {
        float2 v = make_float2(0.f, 0.f);
        if (i < npairs_real) v = ((const float2*)emb)[i];
        emb16[i] = __floats2half2_rn(v.x, v.y);
    }
}

__global__ __launch_bounds__(256) void nnue_fused(
    const int*    __restrict__ x,
    const __half* __restrict__ emb16,
    const float*  __restrict__ W2, const float* __restrict__ b2,
    const float*  __restrict__ W3, const float* __restrict__ b3,
    const float*  __restrict__ W4,
    float*        __restrict__ out, int n)
{
    __shared__ int     xlds[4][512];
    __shared__ __half2 hbuf[64][65];
    __shared__ float   h2T[32 * 64];
    __shared__ float   obuf[4][64];

    const int tid  = threadIdx.x;
    const int lane = tid & 63;
    const int wave = tid >> 6;
    const int row0 = blockIdx.x * RPB;
    const int wrow0 = __builtin_amdgcn_readfirstlane(row0 + wave * 16);
    const int g   = lane >> 4;
    const int sub = lane & 15;
    const unsigned subOff = (unsigned)sub * 16u;

    {
        const int4* xb = (const int4*)(x + (size_t)wrow0 * 32);
        int4 a = xb[lane * 2];
        int4 b = xb[lane * 2 + 1];
        if ((lane & 3) == 3) { b.y = 7424; b.z = 7424; b.w = 7424; }
        ((int4*)&xlds[wave][0])[lane * 2]     = a;
        ((int4*)&xlds[wave][0])[lane * 2 + 1] = b;
    }

    #pragma unroll 4
    for (int r = 0; r < 16; ++r) {
        const int* xrow = &xlds[wave][r * 32 + g];
        uint4 v[8];
        #pragma unroll
        for (int b = 0; b < 8; ++b) {
            const int idx = xrow[4 * b];
            const unsigned off = ((unsigned)idx << 8) + subOff;
            v[b] = *(const uint4*)((const char*)emb16 + off);
        }
        h2v_t hacc[4];
        #pragma unroll
        for (int q = 0; q < 4; ++q) hacc[q] = (h2v_t)0;
        #pragma unroll
        for (int b = 0; b < 8; ++b) {
            hacc[0] += __builtin_bit_cast(h2v_t, v[b].x);
            hacc[1] += __builtin_bit_cast(h2v_t, v[b].y);
            hacc[2] += __builtin_bit_cast(h2v_t, v[b].z);
            hacc[3] += __builtin_bit_cast(h2v_t, v[b].w);
        }
        #pragma unroll
        for (int q = 0; q < 4; ++q) {
            unsigned u = __builtin_bit_cast(unsigned, hacc[q]);
            h2v_t t = __builtin_bit_cast(h2v_t, u);
            t += __builtin_bit_cast(h2v_t, (unsigned)__shfl_xor((int)u, 16));
            unsigned u2 = __builtin_bit_cast(unsigned, t);
            t += __builtin_bit_cast(h2v_t, (unsigned)__shfl_xor((int)u2, 32));
            hacc[q] = __builtin_elementwise_max(t, (h2v_t)0);
        }
        if (g == 0) {
            const int row = wave * 16 + r;
            #pragma unroll
            for (int q = 0; q < 4; ++q)
                hbuf[row][sub * 4 + q] = __builtin_bit_cast(__half2, hacc[q]);
        }
    }
    __syncthreads();

    {
        const int j0 = wave * 8;
        const int rr = lane;
        float acc[8];
        #pragma unroll
        for (int j = 0; j < 8; ++j) acc[j] = b2[j0 + j];
        #pragma unroll
        for (int d2 = 0; d2 < 64; ++d2) {
            const __half2 hv = hbuf[rr][d2];
            const float vx = __low2float(hv), vy = __high2float(hv);
            #pragma unroll
            for (int j = 0; j < 8; ++j) {
                const float* w = W2 + (size_t)(j0 + j) * 128 + d2 * 2;
                acc[j] = fmaf(vx, w[0], acc[j]);
                acc[j] = fmaf(vy, w[1], acc[j]);
            }
        }
        #pragma unroll
        for (int j = 0; j < 8; ++j) h2T[(j0 + j) * 64 + rr] = acc[j];
    }
    __syncthreads();

    {
        const int j0 = wave * 8;
        const int rr = lane;
        float h2v[32];
        #pragma unroll
        for (int k = 0; k < 32; ++k) h2v[k] = h2T[k * 64 + rr];
        float acc[8];
        #pragma unroll
        for (int j = 0; j < 8; ++j) acc[j] = b3[j0 + j];
        #pragma unroll
        for (int k = 0; k < 32; ++k) {
            const float pz = fmaxf(h2v[k], 0.f);
            const float mz = fmaxf(-h2v[k], 0.f);
            #pragma unroll
            for (int j = 0; j < 8; ++j) {
                const float* w = W3 + (size_t)(j0 + j) * 64;
                acc[j] = fmaf(pz, w[k],      acc[j]);
                acc[j] = fmaf(mz, w[32 + k], acc[j]);
            }
        }
        float o = 0.f;
        #pragma unroll
        for (int j = 0; j < 8; ++j) {
            const int jj = j0 + j;
            o = fmaf(fmaxf(acc[j], 0.f),  W4[jj],      o);
            o = fmaf(fmaxf(-acc[j], 0.f), W4[32 + jj], o);
        }
        obuf[wave][rr] = o;
    }
    __syncthreads();

    if (tid < 64) {
        const int row = row0 + tid;
        if (row < n)
            out[row] = obuf[0][tid] + obuf[1][tid] + obuf[2][tid] + obuf[3][tid];
    }
}

extern "C" void kernel_launch(void* const* d_in, const int* in_sizes, int n_in,
                              void* d_out, int out_size, void* d_ws, size_t ws_size,
                              hipStream_t stream) {
    const int*   x   = (const int*)  d_in[0];
    const float* emb = (const float*)d_in[1];
    const float* W2  = (const float*)d_in[2];
    const float* b2  = (const float*)d_in[3];
    const float* W3  = (const float*)d_in[4];
    const float* b3  = (const float*)d_in[5];
    const float* W4  = (const float*)d_in[6];
    float* out = (float*)d_out;
    const int n = out_size;                 // 131072 rows

    // workspace layout (16B-aligned sections)
    const size_t emb8_bytes = (size_t)7425 * 128;           // 950,400
    const size_t w2h_off    = emb8_bytes;                   // +8192
    const size_t w3h_off    = w2h_off + 8192;               // +4096
    const size_t slots_off  = w3h_off + 4096;               // +2048 (512 f32)
    const size_t amax_off   = slots_off + 2048;             // +16
    const size_t need       = amax_off + 16;

    if (ws_size >= need) {
        unsigned*     emb8  = (unsigned*)d_ws;
        _Float16*     W2h   = (_Float16*)((char*)d_ws + w2h_off);
        _Float16*     W3h   = (_Float16*)((char*)d_ws + w3h_off);
        float*        slots = (float*)((char*)d_ws + slots_off);
        float*        amaxp = (float*)((char*)d_ws + amax_off);
        const float4* emb4  = (const float4*)emb;

        const int n4 = 7424 * 32;   // 237,568 float4s
        hipLaunchKernelGGL(absmax_partial, dim3(NSLOTS), dim3(256), 0, stream,
                           emb4, slots, W2, W3, W2h, W3h, n4);

        const int nq = 7425 * 32;   // 237,600 u32s -> 929 blocks
        hipLaunchKernelGGL(prep_q8, dim3((nq + 255) / 256), dim3(256),
                           0, stream, emb4, emb8, slots, amaxp);

        hipLaunchKernelGGL(nnue_q8, dim3((n + RPB - 1) / RPB), dim3(256),
                           0, stream, x, emb8, W2h, W3h, b2, b3, W4,
                           amaxp, out, n);
    } else {
        // legacy fallback: fp16 table + fp32-weight fused kernel
        __half2* emb16 = (__half2*)d_ws;
        const int npairs_real = 7424 * 64;
        const int npairs_tot  = 7425 * 64;
        hipLaunchKernelGGL(prep_fp16, dim3((npairs_tot + 255) / 256), dim3(256),
                           0, stream, emb, emb16, npairs_real, npairs_tot);
        hipLaunchKernelGGL(nnue_fused, dim3((n + RPB - 1) / RPB), dim3(256),
                           0, stream, x, (const __half*)emb16, W2, b2, W3, b3,
                           W4, out, n);
    }
}